// Round 11
// baseline (256.617 us; speedup 1.0000x reference)
//
#include <hip/hip_runtime.h>
#include <hip/hip_fp16.h>
#include <math.h>

#define NN 40000
#define EE 640000
#define NG 64
#define SCAN_BLOCKS ((NN + 1023) / 1024)

__device__ __forceinline__ float eluf(float x) { return x > 0.f ? x : expm1f(x); }

typedef const __attribute__((address_space(1))) char gas_char;
typedef __attribute__((address_space(3))) char las_char;

__device__ __forceinline__ void async_copy16(void* l, const void* g) {
  __builtin_amdgcn_global_load_lds((gas_char*)g, (las_char*)l, 16, 0, 0);
}

typedef __fp16 f16x2 __attribute__((ext_vector_type(2)));
__device__ __forceinline__ unsigned packh(float lo, float hi) {  // f32x2 -> packed fp16
  f16x2 p = __builtin_amdgcn_cvt_pkrtz(lo, hi);
  union { f16x2 h; unsigned u; } c; c.h = p; return c.u;
}
__device__ __forceinline__ float hlo(unsigned p) {
  union { unsigned u; f16x2 h; } c; c.u = p; return (float)c.h.x;
}
__device__ __forceinline__ float hhi(unsigned p) {
  union { unsigned u; f16x2 h; } c; c.u = p; return (float)c.h.y;
}
__device__ __forceinline__ float h16f(unsigned short u) {
  union { unsigned u32; f16x2 h; } c; c.u32 = u; return (float)c.h.x;
}

__global__ void zero_int_kernel(int* __restrict__ p, int n) {
  int i = blockIdx.x * 256 + threadIdx.x;
  if (i < n) p[i] = 0;
}

__global__ void count_deg_kernel(const int* __restrict__ dst, int* __restrict__ deg, int e) {
  int i = blockIdx.x * 256 + threadIdx.x;
  if (i < e) atomicAdd(&deg[dst[i]], 1);
}

__global__ __launch_bounds__(1024) void scanA_kernel(const int* __restrict__ deg,
                                                     int* __restrict__ row_ptr,
                                                     int* __restrict__ bsum, int n) {
  __shared__ int wsum[16];
  int t = threadIdx.x, lane = t & 63, wid = t >> 6;
  int i = blockIdx.x * 1024 + t;
  int v = (i < n) ? deg[i] : 0;
#pragma unroll
  for (int off = 1; off < 64; off <<= 1) {
    int u = __shfl_up(v, off);
    if (lane >= off) v += u;
  }
  if (lane == 63) wsum[wid] = v;
  __syncthreads();
  if (t < 16) {
    int w = wsum[t];
#pragma unroll
    for (int off = 1; off < 16; off <<= 1) {
      int u = __shfl_up(w, off);
      if (t >= off) w += u;
    }
    wsum[t] = w;
  }
  __syncthreads();
  if (wid > 0) v += wsum[wid - 1];
  if (i < n) row_ptr[i + 1] = v;
  if (t == 1023) bsum[blockIdx.x] = v;
}

// scanC with inlined block-offset reduce (scanB merged).
__global__ __launch_bounds__(1024) void scanC_kernel(int* __restrict__ row_ptr,
                                                     const int* __restrict__ bsum,
                                                     int* __restrict__ cursor, int n) {
  __shared__ int off_s;
  int t = threadIdx.x;
  int b = blockIdx.x;
  if (t < 64) {
    int v = (t < b && t < SCAN_BLOCKS) ? bsum[t] : 0;
#pragma unroll
    for (int m = 1; m < 64; m <<= 1) v += __shfl_xor(v, m);
    if (t == 0) off_s = v;
  }
  __syncthreads();
  int off = off_s;
  int i = b * 1024 + t;
  if (i < n) {
    int v = row_ptr[i + 1] + off;
    row_ptr[i + 1] = v;
    if (i + 1 < n) cursor[i + 1] = v;
    if (i == 0) { cursor[0] = 0; row_ptr[0] = 0; }
  }
}

__global__ void scatter_kernel(const int* __restrict__ src, const int* __restrict__ dst,
                               int* __restrict__ cursor, int* __restrict__ csr_src, int e) {
  int i = blockIdx.x * 256 + threadIdx.x;
  if (i < e) {
    int d = dst[i];
    int pos = atomicAdd(&cursor[d], 1);
    csr_src[pos] = src[i];
  }
}

// GEMM (K=128, OUT=128): h = x @ W written as PACKED FP16 pairs.
// LDS 48KB (x k-chunked dbuf 16KB + W dbuf 32KB) -> 3 blocks/CU.
__global__ __launch_bounds__(256, 3) void gemm128_kernel(
    const float* __restrict__ x, const float* __restrict__ W,
    const float* __restrict__ a_s, const float* __restrict__ a_d,
    unsigned* __restrict__ hb, float* __restrict__ als, float* __restrict__ ald)
{
  __shared__ float xs[2][64 * 32];
  __shared__ float ws[2][32 * 128];

  int t = threadIdx.x;
  int row0 = blockIdx.x * 64;
  const char* xgb = (const char*)x + (size_t)row0 * 512;

  {
    int li0 = t, li1 = t + 256;
    async_copy16((char*)xs[0] + li0 * 16, xgb + (li0 >> 3) * 512 + (li0 & 7) * 16);
    async_copy16((char*)xs[0] + li1 * 16, xgb + (li1 >> 3) * 512 + (li1 & 7) * 16);
    const char* wg = (const char*)W;
#pragma unroll
    for (int p = 0; p < 4; ++p)
      async_copy16((char*)ws[0] + p * 4096 + t * 16, wg + p * 4096 + t * 16);
  }
  __syncthreads();

  int cg = t & 31, rg = t >> 5;
  int r0 = rg * 8;
  int jlo = 2 * cg;

  float acc[8][4];
#pragma unroll
  for (int r = 0; r < 8; ++r)
#pragma unroll
    for (int c = 0; c < 4; ++c) acc[r][c] = 0.f;

  for (int ch = 0; ch < 4; ++ch) {
    if (ch < 3) {
      int b = (ch + 1) & 1;
      int li0 = t, li1 = t + 256;
      const char* xg = xgb + (ch + 1) * 128;
      async_copy16((char*)xs[b] + li0 * 16, xg + (li0 >> 3) * 512 + (li0 & 7) * 16);
      async_copy16((char*)xs[b] + li1 * 16, xg + (li1 >> 3) * 512 + (li1 & 7) * 16);
      const char* wg = (const char*)W + (size_t)(ch + 1) * 32 * 128 * 4;
#pragma unroll
      for (int p = 0; p < 4; ++p)
        async_copy16((char*)ws[b] + p * 4096 + t * 16, wg + p * 4096 + t * 16);
    }
    const float* wc = ws[ch & 1];
    const float* xc = xs[ch & 1];
#pragma unroll
    for (int kk = 0; kk < 32; kk += 4) {
      float2 wlo[4], whi[4];
#pragma unroll
      for (int q = 0; q < 4; ++q) {
        wlo[q] = *reinterpret_cast<const float2*>(&wc[(kk + q) * 128 + jlo]);
        whi[q] = *reinterpret_cast<const float2*>(&wc[(kk + q) * 128 + 64 + jlo]);
      }
#pragma unroll
      for (int r = 0; r < 8; ++r) {
        float4 xv = *reinterpret_cast<const float4*>(&xc[(r0 + r) * 32 + kk]);
        float a0 = acc[r][0], a1 = acc[r][1], a2 = acc[r][2], a3 = acc[r][3];
        a0 = fmaf(xv.x, wlo[0].x, a0); a1 = fmaf(xv.x, wlo[0].y, a1);
        a2 = fmaf(xv.x, whi[0].x, a2); a3 = fmaf(xv.x, whi[0].y, a3);
        a0 = fmaf(xv.y, wlo[1].x, a0); a1 = fmaf(xv.y, wlo[1].y, a1);
        a2 = fmaf(xv.y, whi[1].x, a2); a3 = fmaf(xv.y, whi[1].y, a3);
        a0 = fmaf(xv.z, wlo[2].x, a0); a1 = fmaf(xv.z, wlo[2].y, a1);
        a2 = fmaf(xv.z, whi[2].x, a2); a3 = fmaf(xv.z, whi[2].y, a3);
        a0 = fmaf(xv.w, wlo[3].x, a0); a1 = fmaf(xv.w, wlo[3].y, a1);
        a2 = fmaf(xv.w, whi[3].x, a2); a3 = fmaf(xv.w, whi[3].y, a3);
        acc[r][0] = a0; acc[r][1] = a1; acc[r][2] = a2; acc[r][3] = a3;
      }
    }
    __syncthreads();
  }

#pragma unroll
  for (int r = 0; r < 8; ++r) {
    uint2 pv;
    pv.x = packh(acc[r][0], acc[r][2]);
    pv.y = packh(acc[r][1], acc[r][3]);
    *reinterpret_cast<uint2*>(&hb[(size_t)(row0 + r0 + r) * 64 + jlo]) = pv;
  }

  float as0 = a_s[jlo], as1 = a_s[jlo + 1], as2 = a_s[jlo + 64], as3 = a_s[jlo + 65];
  float ad0 = a_d[jlo], ad1 = a_d[jlo + 1], ad2 = a_d[jlo + 64], ad3 = a_d[jlo + 65];
  int lane = t & 63;
#pragma unroll
  for (int r = 0; r < 8; ++r) {
    float psa = fmaf(acc[r][0], as0, acc[r][1] * as1);
    float psb = fmaf(acc[r][2], as2, acc[r][3] * as3);
    float pda = fmaf(acc[r][0], ad0, acc[r][1] * ad1);
    float pdb = fmaf(acc[r][2], ad2, acc[r][3] * ad3);
#pragma unroll
    for (int m = 1; m < 16; m <<= 1) {
      psa += __shfl_xor(psa, m); psb += __shfl_xor(psb, m);
      pda += __shfl_xor(pda, m); pdb += __shfl_xor(pdb, m);
    }
    if ((lane & 15) == 0) {
      int hA = (lane >> 4) & 1;
      size_t row = (size_t)(row0 + r0 + r);
      als[row * 4 + hA] = psa; als[row * 4 + hA + 2] = psb;
      ald[row * 4 + hA] = pda; ald[row * 4 + hA + 2] = pdb;
    }
  }
}

// Aggregate for OUT=128, half-wave per node (8 nodes / 256-thread block).
// FUSE=true: instead of writing the 128-dim output row, multiply it by W2
// (128x32, staged transposed in LDS) and emit h2 (fp16) + als2/ald2 for
// layer 2 -- eliminates the separate gemm32 kernel and the B2 round-trip.
template<bool FUSE>
__global__ __launch_bounds__(256) void aggregate128_kernel(
    const unsigned* __restrict__ hb, const float* __restrict__ als, const float* __restrict__ ald,
    const int* __restrict__ row_ptr, const int* __restrict__ csr_src,
    const float* __restrict__ bias, const float* __restrict__ ln_g, const float* __restrict__ ln_b,
    float* __restrict__ out,
    const float* __restrict__ W2, const float* __restrict__ as2, const float* __restrict__ ad2,
    unsigned short* __restrict__ h2h, float* __restrict__ als2, float* __restrict__ ald2)
{
  __shared__ int s_src[4][2][32];
  __shared__ float2 s_w[4][2][32][2];
  __shared__ __align__(16) float w2t[FUSE ? 32 * 132 : 4];
  __shared__ __align__(16) float y_s[FUSE ? 8 * 128 : 4];

  int t = threadIdx.x, lane = t & 63, wid = t >> 6;
  int hw = lane >> 5, c = lane & 31;
  int node = blockIdx.x * 8 + wid * 2 + hw;   // N = 40000 = 5000*8 exact

  if constexpr (FUSE) {
    // stage W2 transposed: w2t[c][k], stride 132 (16B-aligned, 4-way conflict)
#pragma unroll
    for (int i = 0; i < 16; ++i) {
      int e = i * 256 + t;
      w2t[(e & 31) * 132 + (e >> 5)] = W2[e];
    }
    __syncthreads();
  }

  int start = row_ptr[node], end = row_ptr[node + 1];
  int deg = end - start;

  float4 adq = reinterpret_cast<const float4*>(ald)[node];
  int hsel = c >> 4;                 // head pair (hsel, hsel+2)
  float a0 = 0.f, a1 = 0.f, a2 = 0.f, a3 = 0.f;
  float ssum0 = 0.f, ssum1 = 0.f;

  if (deg <= 32) {
    int s = 0;
    float ex0 = 0.f, ex1 = 0.f, ex2 = 0.f, ex3 = 0.f;
    if (c < deg) {
      s = csr_src[start + c];
      float4 q = reinterpret_cast<const float4*>(als)[s];
      float v0 = q.x + adq.x, v1 = q.y + adq.y, v2 = q.z + adq.z, v3 = q.w + adq.w;
      v0 = v0 > 0.f ? v0 : 0.2f * v0; v1 = v1 > 0.f ? v1 : 0.2f * v1;
      v2 = v2 > 0.f ? v2 : 0.2f * v2; v3 = v3 > 0.f ? v3 : 0.2f * v3;
      ex0 = __expf(v0); ex1 = __expf(v1); ex2 = __expf(v2); ex3 = __expf(v3);
    }
    s_src[wid][hw][c] = s;
    s_w[wid][hw][c][0] = make_float2(ex0, ex2);
    s_w[wid][hw][c][1] = make_float2(ex1, ex3);

    float b0a = 0.f, b1a = 0.f, b2a = 0.f, b3a = 0.f;
    float sb0 = 0.f, sb1 = 0.f;
    int j = 0;
    for (; j + 2 <= deg; j += 2) {
      int sa = s_src[wid][hw][j];
      int sb = s_src[wid][hw][j + 1];
      uint2 ua = *reinterpret_cast<const uint2*>(&hb[(size_t)sa * 64 + 2 * c]);
      uint2 ub = *reinterpret_cast<const uint2*>(&hb[(size_t)sb * 64 + 2 * c]);
      float2 wa = s_w[wid][hw][j][hsel];
      float2 wb = s_w[wid][hw][j + 1][hsel];
      a0 = fmaf(wa.x, hlo(ua.x), a0); a1 = fmaf(wa.x, hlo(ua.y), a1);
      a2 = fmaf(wa.y, hhi(ua.x), a2); a3 = fmaf(wa.y, hhi(ua.y), a3);
      ssum0 += wa.x; ssum1 += wa.y;
      b0a = fmaf(wb.x, hlo(ub.x), b0a); b1a = fmaf(wb.x, hlo(ub.y), b1a);
      b2a = fmaf(wb.y, hhi(ub.x), b2a); b3a = fmaf(wb.y, hhi(ub.y), b3a);
      sb0 += wb.x; sb1 += wb.y;
    }
    if (j < deg) {
      int sa = s_src[wid][hw][j];
      uint2 ua = *reinterpret_cast<const uint2*>(&hb[(size_t)sa * 64 + 2 * c]);
      float2 wa = s_w[wid][hw][j][hsel];
      a0 = fmaf(wa.x, hlo(ua.x), a0); a1 = fmaf(wa.x, hlo(ua.y), a1);
      a2 = fmaf(wa.y, hhi(ua.x), a2); a3 = fmaf(wa.y, hhi(ua.y), a3);
      ssum0 += wa.x; ssum1 += wa.y;
    }
    a0 += b0a; a1 += b1a; a2 += b2a; a3 += b3a;
    ssum0 += sb0; ssum1 += sb1;
  } else {
    // chunked fallback (deg > 32: rare at avg degree 16)
    for (int eb = 0; eb < deg; eb += 32) {
      int s = 0;
      float ex0 = 0.f, ex1 = 0.f, ex2 = 0.f, ex3 = 0.f;
      if (eb + c < deg) {
        s = csr_src[start + eb + c];
        float4 q = reinterpret_cast<const float4*>(als)[s];
        float v0 = q.x + adq.x, v1 = q.y + adq.y, v2 = q.z + adq.z, v3 = q.w + adq.w;
        v0 = v0 > 0.f ? v0 : 0.2f * v0; v1 = v1 > 0.f ? v1 : 0.2f * v1;
        v2 = v2 > 0.f ? v2 : 0.2f * v2; v3 = v3 > 0.f ? v3 : 0.2f * v3;
        ex0 = __expf(v0); ex1 = __expf(v1); ex2 = __expf(v2); ex3 = __expf(v3);
      }
      s_src[wid][hw][c] = s;
      s_w[wid][hw][c][0] = make_float2(ex0, ex2);
      s_w[wid][hw][c][1] = make_float2(ex1, ex3);
      int cnt = deg - eb; if (cnt > 32) cnt = 32;
      for (int j = 0; j < cnt; ++j) {
        int sj = s_src[wid][hw][j];
        uint2 u = *reinterpret_cast<const uint2*>(&hb[(size_t)sj * 64 + 2 * c]);
        float2 w = s_w[wid][hw][j][hsel];
        a0 = fmaf(w.x, hlo(u.x), a0); a1 = fmaf(w.x, hlo(u.y), a1);
        a2 = fmaf(w.y, hhi(u.x), a2); a3 = fmaf(w.y, hhi(u.y), a3);
        ssum0 += w.x; ssum1 += w.y;
      }
    }
  }

  float2 blo = *reinterpret_cast<const float2*>(&bias[2 * c]);
  float2 bhi = *reinterpret_cast<const float2*>(&bias[2 * c + 64]);
  float is0 = 1.f / (ssum0 + 1e-16f), is1 = 1.f / (ssum1 + 1e-16f);
  float o0 = a0 * is0 + blo.x;
  float o1 = a1 * is0 + blo.y;
  float o2 = a2 * is1 + bhi.x;
  float o3 = a3 * is1 + bhi.y;
  float red = o0 + o1 + o2 + o3;
  float sq2 = o0 * o0 + o1 * o1 + o2 * o2 + o3 * o3;
#pragma unroll
  for (int m = 1; m < 32; m <<= 1) {
    red += __shfl_xor(red, m);
    sq2 += __shfl_xor(sq2, m);
  }
  float mu = red * (1.f / 128.f);
  float var = sq2 * (1.f / 128.f) - mu * mu;
  float rstd = rsqrtf(var + 1e-5f);
  float2 glo = *reinterpret_cast<const float2*>(&ln_g[2 * c]);
  float2 ghi = *reinterpret_cast<const float2*>(&ln_g[2 * c + 64]);
  float2 bl2 = *reinterpret_cast<const float2*>(&ln_b[2 * c]);
  float2 bh2 = *reinterpret_cast<const float2*>(&ln_b[2 * c + 64]);
  float2 ylo, yhi;
  ylo.x = eluf((o0 - mu) * rstd * glo.x + bl2.x);
  ylo.y = eluf((o1 - mu) * rstd * glo.y + bl2.y);
  yhi.x = eluf((o2 - mu) * rstd * ghi.x + bh2.x);
  yhi.y = eluf((o3 - mu) * rstd * ghi.y + bh2.y);

  if constexpr (!FUSE) {
    *reinterpret_cast<float2*>(&out[(size_t)node * 128 + 2 * c]) = ylo;
    *reinterpret_cast<float2*>(&out[(size_t)node * 128 + 64 + 2 * c]) = yhi;
  } else {
    // broadcast y through LDS (wave-synchronous within the half-wave)
    int nidx = (wid * 2 + hw) * 128;
    *reinterpret_cast<float2*>(&y_s[nidx + 2 * c]) = ylo;
    *reinterpret_cast<float2*>(&y_s[nidx + 64 + 2 * c]) = yhi;
    // h2[node][c] = y . W2[:,c]
    float acc = 0.f;
    const float* wrow = &w2t[c * 132];
#pragma unroll
    for (int k = 0; k < 128; k += 4) {
      float4 yv = *reinterpret_cast<const float4*>(&y_s[nidx + k]);
      float4 wv = *reinterpret_cast<const float4*>(&wrow[k]);
      acc = fmaf(yv.x, wv.x, acc); acc = fmaf(yv.y, wv.y, acc);
      acc = fmaf(yv.z, wv.z, acc); acc = fmaf(yv.w, wv.w, acc);
    }
    h2h[(size_t)node * 32 + c] = (unsigned short)(packh(acc, acc) & 0xffffu);
    float ps = acc * as2[c], pd = acc * ad2[c];
#pragma unroll
    for (int m = 1; m < 32; m <<= 1) { ps += __shfl_xor(ps, m); pd += __shfl_xor(pd, m); }
    if (c == 0) { als2[node] = ps; ald2[node] = pd; }
  }
}

// Aggregate for OUT=32 (fp16 h rows, 2B/feature). Half-wave per node.
__global__ __launch_bounds__(256) void aggregate32_kernel(
    const unsigned short* __restrict__ h, const float* __restrict__ als, const float* __restrict__ ald,
    const int* __restrict__ row_ptr, const int* __restrict__ csr_src,
    const float* __restrict__ bias, const float* __restrict__ ln_g, const float* __restrict__ ln_b,
    float* __restrict__ out, int n)
{
  __shared__ int s_src[4][2][32];
  __shared__ float s_ex[4][2][32];
  int t = threadIdx.x, lane = t & 63, wid = t >> 6;
  int hw = lane >> 5, c = lane & 31;
  int node = blockIdx.x * 8 + wid * 2 + hw;
  int start = row_ptr[node], end = row_ptr[node + 1];
  int deg = end - start;
  float adl = ald[node];
  float acc0 = 0.f, ssum = 0.f;

  if (deg <= 32) {
    int s = 0; float ex = 0.f;
    if (c < deg) {
      s = csr_src[start + c];
      float v = als[s] + adl;
      v = v > 0.f ? v : 0.2f * v;
      ex = __expf(v);
    }
    s_src[wid][hw][c] = s;
    s_ex[wid][hw][c] = ex;

    float acc1 = 0.f, ssum1 = 0.f;
    int j = 0;
    for (; j + 2 <= deg; j += 2) {
      int sa = s_src[wid][hw][j];
      int sb = s_src[wid][hw][j + 1];
      float ha = h16f(h[(size_t)sa * 32 + c]);
      float hbv = h16f(h[(size_t)sb * 32 + c]);
      float wa = s_ex[wid][hw][j];
      float wb = s_ex[wid][hw][j + 1];
      acc0 = fmaf(wa, ha, acc0); ssum += wa;
      acc1 = fmaf(wb, hbv, acc1); ssum1 += wb;
    }
    if (j < deg) {
      float wa = s_ex[wid][hw][j];
      acc0 = fmaf(wa, h16f(h[(size_t)s_src[wid][hw][j] * 32 + c]), acc0);
      ssum += wa;
    }
    acc0 += acc1; ssum += ssum1;
  } else {
    for (int eb = 0; eb < deg; eb += 32) {
      int s = 0; float ex = 0.f;
      if (eb + c < deg) {
        s = csr_src[start + eb + c];
        float v = als[s] + adl;
        v = v > 0.f ? v : 0.2f * v;
        ex = __expf(v);
      }
      s_src[wid][hw][c] = s;
      s_ex[wid][hw][c] = ex;
      int cnt = deg - eb; if (cnt > 32) cnt = 32;
      for (int j = 0; j < cnt; ++j) {
        float w = s_ex[wid][hw][j];
        acc0 = fmaf(w, h16f(h[(size_t)s_src[wid][hw][j] * 32 + c]), acc0);
        ssum += w;
      }
    }
  }

  float o0 = acc0 / (ssum + 1e-16f) + bias[c];
  float red = o0, sq2 = o0 * o0;
#pragma unroll
  for (int m = 1; m < 32; m <<= 1) {
    red += __shfl_xor(red, m);
    sq2 += __shfl_xor(sq2, m);
  }
  float mu = red * (1.f / 32.f);
  float var = sq2 * (1.f / 32.f) - mu * mu;
  float rstd = rsqrtf(var + 1e-5f);
  float y0 = (o0 - mu) * rstd * ln_g[c] + ln_b[c];
  out[(size_t)node * 32 + c] = eluf(y0);
}

__device__ __forceinline__ int lower_bound_dev(const int* a, int n, int key) {
  int lo = 0, hi = n;
  while (lo < hi) { int mid = (lo + hi) >> 1; if (a[mid] < key) lo = mid + 1; else hi = mid; }
  return lo;
}

// Fused global mean-pool + 2-layer classifier: one block per group.
__global__ __launch_bounds__(256) void poolfc_kernel(
    const float* __restrict__ x2, const int* __restrict__ batch,
    const float* __restrict__ fc1w, const float* __restrict__ fc1b,
    const float* __restrict__ fc2w, const float* __restrict__ fc2b,
    float* __restrict__ out, int n)
{
  int g = blockIdx.x;
  int lo = lower_bound_dev(batch, n, g);
  int hi = lower_bound_dev(batch, n, g + 1);
  int t = threadIdx.x;
  int c = t & 31, r = t >> 5;
  float acc = 0.f;
  for (int i = lo + r; i < hi; i += 8) acc += x2[(size_t)i * 32 + c];
  __shared__ float red[8][32];
  __shared__ float hgl[32];
  __shared__ float zl[16];
  red[r][c] = acc;
  __syncthreads();
  if (r == 0) {
    float s = 0.f;
#pragma unroll
    for (int k = 0; k < 8; ++k) s += red[k][c];
    float cnt = (float)(hi - lo);
    hgl[c] = s / fmaxf(cnt, 1.f);
  }
  __syncthreads();
  if (t < 16) {
    float a = fc1b[t];
#pragma unroll
    for (int k = 0; k < 32; ++k) a = fmaf(hgl[k], fc1w[k * 16 + t], a);
    zl[t] = fmaxf(a, 0.f);
  }
  __syncthreads();
  if (t < 2) {
    float a = fc2b[t];
#pragma unroll
    for (int j = 0; j < 16; ++j) a = fmaf(zl[j], fc2w[j * 2 + t], a);
    out[g * 2 + t] = a;
  }
}

extern "C" void kernel_launch(void* const* d_in, const int* in_sizes, int n_in,
                              void* d_out, int out_size, void* d_ws, size_t ws_size,
                              hipStream_t stream) {
  const float* x    = (const float*)d_in[0];
  const int*   ei   = (const int*)d_in[1];
  const int*   batch= (const int*)d_in[2];
  const float* W0   = (const float*)d_in[3];
  const float* as0  = (const float*)d_in[4];
  const float* ad0  = (const float*)d_in[5];
  const float* b0   = (const float*)d_in[6];
  const float* ln0g = (const float*)d_in[7];
  const float* ln0b = (const float*)d_in[8];
  const float* W1   = (const float*)d_in[9];
  const float* as1  = (const float*)d_in[10];
  const float* ad1  = (const float*)d_in[11];
  const float* b1   = (const float*)d_in[12];
  const float* ln1g = (const float*)d_in[13];
  const float* ln1b = (const float*)d_in[14];
  const float* W2   = (const float*)d_in[15];
  const float* as2  = (const float*)d_in[16];
  const float* ad2  = (const float*)d_in[17];
  const float* b2   = (const float*)d_in[18];
  const float* ln2g = (const float*)d_in[19];
  const float* ln2b = (const float*)d_in[20];
  const float* fc1w = (const float*)d_in[21];
  const float* fc1b = (const float*)d_in[22];
  const float* fc2w = (const float*)d_in[23];
  const float* fc2b = (const float*)d_in[24];
  float* out = (float*)d_out;

  const int* srce = ei;
  const int* dste = ei + EE;

  unsigned* hb = (unsigned*)d_ws;              // N*64 packed fp16 pairs
  float* B2  = (float*)(hb + (size_t)NN * 64); // N*128
  float* als = B2 + (size_t)NN * 128;          // N*4
  float* ald = als + (size_t)NN * 4;           // N*4
  unsigned short* h2h = (unsigned short*)(ald + (size_t)NN * 4); // N*32 fp16
  float* x2  = (float*)(h2h + (size_t)NN * 32);// N*32
  float* als2 = x2 + (size_t)NN * 32;          // N
  float* ald2 = als2 + NN;                     // N
  int* deg      = (int*)(ald2 + NN);           // N
  int* row_ptr  = deg + NN;                    // N+1
  int* cursor   = row_ptr + NN + 1;            // N
  int* csr_src  = cursor + NN;                 // E
  int* bsum     = csr_src + EE;                // SCAN_BLOCKS

  // CSR build (shared by all 3 layers)
  zero_int_kernel<<<(NN + 255) / 256, 256, 0, stream>>>(deg, NN);
  count_deg_kernel<<<(EE + 255) / 256, 256, 0, stream>>>(dste, deg, EE);
  scanA_kernel<<<SCAN_BLOCKS, 1024, 0, stream>>>(deg, row_ptr, bsum, NN);
  scanC_kernel<<<SCAN_BLOCKS, 1024, 0, stream>>>(row_ptr, bsum, cursor, NN);
  scatter_kernel<<<(EE + 255) / 256, 256, 0, stream>>>(srce, dste, cursor, csr_src, EE);

  // layer 0
  gemm128_kernel<<<625, 256, 0, stream>>>(x, W0, as0, ad0, hb, als, ald);
  aggregate128_kernel<false><<<NN / 8, 256, 0, stream>>>(hb, als, ald, row_ptr, csr_src,
                                                         b0, ln0g, ln0b, B2,
                                                         nullptr, nullptr, nullptr,
                                                         nullptr, nullptr, nullptr);
  // layer 1 (+ fused layer-2 GEMM and attention projections)
  gemm128_kernel<<<625, 256, 0, stream>>>(B2, W1, as1, ad1, hb, als, ald);
  aggregate128_kernel<true><<<NN / 8, 256, 0, stream>>>(hb, als, ald, row_ptr, csr_src,
                                                        b1, ln1g, ln1b, nullptr,
                                                        W2, as2, ad2, h2h, als2, ald2);
  // layer 2 aggregate
  aggregate32_kernel<<<NN / 8, 256, 0, stream>>>(h2h, als2, ald2, row_ptr, csr_src,
                                                 b2, ln2g, ln2b, x2, NN);
  // pool + classifier (fused)
  poolfc_kernel<<<NG, 256, 0, stream>>>(x2, batch, fc1w, fc1b, fc2w, fc2b, out, NN);
}

// Round 12
// 254.591 us; speedup vs baseline: 1.0080x; 1.0080x over previous
//
#include <hip/hip_runtime.h>
#include <hip/hip_fp16.h>
#include <math.h>

#define NN 40000
#define EE 640000
#define NG 64
#define SCAN_BLOCKS ((NN + 1023) / 1024)

__device__ __forceinline__ float eluf(float x) { return x > 0.f ? x : expm1f(x); }

typedef const __attribute__((address_space(1))) char gas_char;
typedef __attribute__((address_space(3))) char las_char;

__device__ __forceinline__ void async_copy16(void* l, const void* g) {
  __builtin_amdgcn_global_load_lds((gas_char*)g, (las_char*)l, 16, 0, 0);
}

typedef __fp16 f16x2 __attribute__((ext_vector_type(2)));
__device__ __forceinline__ unsigned packh(float lo, float hi) {  // f32x2 -> packed fp16
  f16x2 p = __builtin_amdgcn_cvt_pkrtz(lo, hi);
  union { f16x2 h; unsigned u; } c; c.h = p; return c.u;
}
__device__ __forceinline__ float hlo(unsigned p) {
  union { unsigned u; f16x2 h; } c; c.u = p; return (float)c.h.x;
}
__device__ __forceinline__ float hhi(unsigned p) {
  union { unsigned u; f16x2 h; } c; c.u = p; return (float)c.h.y;
}
__device__ __forceinline__ float h16f(unsigned short u) {
  union { unsigned u32; f16x2 h; } c; c.u32 = u; return (float)c.h.x;
}

__global__ void zero_int_kernel(int* __restrict__ p, int n) {
  int i = blockIdx.x * 256 + threadIdx.x;
  if (i < n) p[i] = 0;
}

// 4 edges/thread, int4 loads, 4 independent atomic chains.
__global__ void count_deg_kernel(const int* __restrict__ dst, int* __restrict__ deg, int e) {
  int i0 = (blockIdx.x * 256 + threadIdx.x) * 4;
  if (i0 + 4 <= e) {
    int4 d4 = *reinterpret_cast<const int4*>(&dst[i0]);
    atomicAdd(&deg[d4.x], 1);
    atomicAdd(&deg[d4.y], 1);
    atomicAdd(&deg[d4.z], 1);
    atomicAdd(&deg[d4.w], 1);
  } else {
    for (int i = i0; i < e; ++i) atomicAdd(&deg[dst[i]], 1);
  }
}

__global__ __launch_bounds__(1024) void scanA_kernel(const int* __restrict__ deg,
                                                     int* __restrict__ row_ptr,
                                                     int* __restrict__ bsum, int n) {
  __shared__ int wsum[16];
  int t = threadIdx.x, lane = t & 63, wid = t >> 6;
  int i = blockIdx.x * 1024 + t;
  int v = (i < n) ? deg[i] : 0;
#pragma unroll
  for (int off = 1; off < 64; off <<= 1) {
    int u = __shfl_up(v, off);
    if (lane >= off) v += u;
  }
  if (lane == 63) wsum[wid] = v;
  __syncthreads();
  if (t < 16) {
    int w = wsum[t];
#pragma unroll
    for (int off = 1; off < 16; off <<= 1) {
      int u = __shfl_up(w, off);
      if (t >= off) w += u;
    }
    wsum[t] = w;
  }
  __syncthreads();
  if (wid > 0) v += wsum[wid - 1];
  if (i < n) row_ptr[i + 1] = v;
  if (t == 1023) bsum[blockIdx.x] = v;
}

// scanC with inlined block-offset reduce (scanB merged).
__global__ __launch_bounds__(1024) void scanC_kernel(int* __restrict__ row_ptr,
                                                     const int* __restrict__ bsum,
                                                     int* __restrict__ cursor, int n) {
  __shared__ int off_s;
  int t = threadIdx.x;
  int b = blockIdx.x;
  if (t < 64) {
    int v = (t < b && t < SCAN_BLOCKS) ? bsum[t] : 0;
#pragma unroll
    for (int m = 1; m < 64; m <<= 1) v += __shfl_xor(v, m);
    if (t == 0) off_s = v;
  }
  __syncthreads();
  int off = off_s;
  int i = b * 1024 + t;
  if (i < n) {
    int v = row_ptr[i + 1] + off;
    row_ptr[i + 1] = v;
    if (i + 1 < n) cursor[i + 1] = v;
    if (i == 0) { cursor[0] = 0; row_ptr[0] = 0; }
  }
}

// 4 edges/thread: int4 loads of src/dst, 4 independent atomic->store chains.
__global__ void scatter_kernel(const int* __restrict__ src, const int* __restrict__ dst,
                               int* __restrict__ cursor, int* __restrict__ csr_src, int e) {
  int i0 = (blockIdx.x * 256 + threadIdx.x) * 4;
  if (i0 + 4 <= e) {
    int4 s4 = *reinterpret_cast<const int4*>(&src[i0]);
    int4 d4 = *reinterpret_cast<const int4*>(&dst[i0]);
    int p0 = atomicAdd(&cursor[d4.x], 1);
    int p1 = atomicAdd(&cursor[d4.y], 1);
    int p2 = atomicAdd(&cursor[d4.z], 1);
    int p3 = atomicAdd(&cursor[d4.w], 1);
    csr_src[p0] = s4.x;
    csr_src[p1] = s4.y;
    csr_src[p2] = s4.z;
    csr_src[p3] = s4.w;
  } else {
    for (int i = i0; i < e; ++i) {
      int d = dst[i];
      int pos = atomicAdd(&cursor[d], 1);
      csr_src[pos] = src[i];
    }
  }
}

// GEMM (K=128, OUT=128): h = x @ W written as PACKED FP16 pairs.
// LDS 48KB (x k-chunked dbuf 16KB + W dbuf 32KB) -> 3 blocks/CU.
__global__ __launch_bounds__(256, 3) void gemm128_kernel(
    const float* __restrict__ x, const float* __restrict__ W,
    const float* __restrict__ a_s, const float* __restrict__ a_d,
    unsigned* __restrict__ hb, float* __restrict__ als, float* __restrict__ ald)
{
  __shared__ float xs[2][64 * 32];
  __shared__ float ws[2][32 * 128];

  int t = threadIdx.x;
  int row0 = blockIdx.x * 64;
  const char* xgb = (const char*)x + (size_t)row0 * 512;

  {
    int li0 = t, li1 = t + 256;
    async_copy16((char*)xs[0] + li0 * 16, xgb + (li0 >> 3) * 512 + (li0 & 7) * 16);
    async_copy16((char*)xs[0] + li1 * 16, xgb + (li1 >> 3) * 512 + (li1 & 7) * 16);
    const char* wg = (const char*)W;
#pragma unroll
    for (int p = 0; p < 4; ++p)
      async_copy16((char*)ws[0] + p * 4096 + t * 16, wg + p * 4096 + t * 16);
  }
  __syncthreads();

  int cg = t & 31, rg = t >> 5;
  int r0 = rg * 8;
  int jlo = 2 * cg;

  float acc[8][4];
#pragma unroll
  for (int r = 0; r < 8; ++r)
#pragma unroll
    for (int c = 0; c < 4; ++c) acc[r][c] = 0.f;

  for (int ch = 0; ch < 4; ++ch) {
    if (ch < 3) {
      int b = (ch + 1) & 1;
      int li0 = t, li1 = t + 256;
      const char* xg = xgb + (ch + 1) * 128;
      async_copy16((char*)xs[b] + li0 * 16, xg + (li0 >> 3) * 512 + (li0 & 7) * 16);
      async_copy16((char*)xs[b] + li1 * 16, xg + (li1 >> 3) * 512 + (li1 & 7) * 16);
      const char* wg = (const char*)W + (size_t)(ch + 1) * 32 * 128 * 4;
#pragma unroll
      for (int p = 0; p < 4; ++p)
        async_copy16((char*)ws[b] + p * 4096 + t * 16, wg + p * 4096 + t * 16);
    }
    const float* wc = ws[ch & 1];
    const float* xc = xs[ch & 1];
#pragma unroll
    for (int kk = 0; kk < 32; kk += 4) {
      float2 wlo[4], whi[4];
#pragma unroll
      for (int q = 0; q < 4; ++q) {
        wlo[q] = *reinterpret_cast<const float2*>(&wc[(kk + q) * 128 + jlo]);
        whi[q] = *reinterpret_cast<const float2*>(&wc[(kk + q) * 128 + 64 + jlo]);
      }
#pragma unroll
      for (int r = 0; r < 8; ++r) {
        float4 xv = *reinterpret_cast<const float4*>(&xc[(r0 + r) * 32 + kk]);
        float a0 = acc[r][0], a1 = acc[r][1], a2 = acc[r][2], a3 = acc[r][3];
        a0 = fmaf(xv.x, wlo[0].x, a0); a1 = fmaf(xv.x, wlo[0].y, a1);
        a2 = fmaf(xv.x, whi[0].x, a2); a3 = fmaf(xv.x, whi[0].y, a3);
        a0 = fmaf(xv.y, wlo[1].x, a0); a1 = fmaf(xv.y, wlo[1].y, a1);
        a2 = fmaf(xv.y, whi[1].x, a2); a3 = fmaf(xv.y, whi[1].y, a3);
        a0 = fmaf(xv.z, wlo[2].x, a0); a1 = fmaf(xv.z, wlo[2].y, a1);
        a2 = fmaf(xv.z, whi[2].x, a2); a3 = fmaf(xv.z, whi[2].y, a3);
        a0 = fmaf(xv.w, wlo[3].x, a0); a1 = fmaf(xv.w, wlo[3].y, a1);
        a2 = fmaf(xv.w, whi[3].x, a2); a3 = fmaf(xv.w, whi[3].y, a3);
        acc[r][0] = a0; acc[r][1] = a1; acc[r][2] = a2; acc[r][3] = a3;
      }
    }
    __syncthreads();
  }

#pragma unroll
  for (int r = 0; r < 8; ++r) {
    uint2 pv;
    pv.x = packh(acc[r][0], acc[r][2]);
    pv.y = packh(acc[r][1], acc[r][3]);
    *reinterpret_cast<uint2*>(&hb[(size_t)(row0 + r0 + r) * 64 + jlo]) = pv;
  }

  float as0 = a_s[jlo], as1 = a_s[jlo + 1], as2 = a_s[jlo + 64], as3 = a_s[jlo + 65];
  float ad0 = a_d[jlo], ad1 = a_d[jlo + 1], ad2 = a_d[jlo + 64], ad3 = a_d[jlo + 65];
  int lane = t & 63;
#pragma unroll
  for (int r = 0; r < 8; ++r) {
    float psa = fmaf(acc[r][0], as0, acc[r][1] * as1);
    float psb = fmaf(acc[r][2], as2, acc[r][3] * as3);
    float pda = fmaf(acc[r][0], ad0, acc[r][1] * ad1);
    float pdb = fmaf(acc[r][2], ad2, acc[r][3] * ad3);
#pragma unroll
    for (int m = 1; m < 16; m <<= 1) {
      psa += __shfl_xor(psa, m); psb += __shfl_xor(psb, m);
      pda += __shfl_xor(pda, m); pdb += __shfl_xor(pdb, m);
    }
    if ((lane & 15) == 0) {
      int hA = (lane >> 4) & 1;
      size_t row = (size_t)(row0 + r0 + r);
      als[row * 4 + hA] = psa; als[row * 4 + hA + 2] = psb;
      ald[row * 4 + hA] = pda; ald[row * 4 + hA + 2] = pdb;
    }
  }
}

// Aggregate for OUT=128, half-wave per node (8 nodes / 256-thread block).
// FUSE=true: multiply the finished 128-dim row by W2 (staged UNtransposed in
// LDS: w2s[k*32+c] -> lane c reads bank c, conflict-free; y reads broadcast)
// with a 4-way split accumulator chain; emit fp16 h2 + als2/ald2.
template<bool FUSE>
__global__ __launch_bounds__(256) void aggregate128_kernel(
    const unsigned* __restrict__ hb, const float* __restrict__ als, const float* __restrict__ ald,
    const int* __restrict__ row_ptr, const int* __restrict__ csr_src,
    const float* __restrict__ bias, const float* __restrict__ ln_g, const float* __restrict__ ln_b,
    float* __restrict__ out,
    const float* __restrict__ W2, const float* __restrict__ as2, const float* __restrict__ ad2,
    unsigned short* __restrict__ h2h, float* __restrict__ als2, float* __restrict__ ald2)
{
  __shared__ int s_src[4][2][32];
  __shared__ float2 s_w[4][2][32][2];
  __shared__ __align__(16) float w2s[FUSE ? 32 * 128 : 4];
  __shared__ __align__(16) float y_s[FUSE ? 8 * 128 : 4];

  int t = threadIdx.x, lane = t & 63, wid = t >> 6;
  int hw = lane >> 5, c = lane & 31;
  int node = blockIdx.x * 8 + wid * 2 + hw;   // N = 40000 = 5000*8 exact

  if constexpr (FUSE) {
    // stage W2 as-is (row-major 128x32): 16KB via async copies
#pragma unroll
    for (int p = 0; p < 4; ++p)
      async_copy16((char*)w2s + p * 4096 + t * 16, (const char*)W2 + p * 4096 + t * 16);
    __syncthreads();
  }

  int start = row_ptr[node], end = row_ptr[node + 1];
  int deg = end - start;

  float4 adq = reinterpret_cast<const float4*>(ald)[node];
  int hsel = c >> 4;                 // head pair (hsel, hsel+2)
  float a0 = 0.f, a1 = 0.f, a2 = 0.f, a3 = 0.f;
  float ssum0 = 0.f, ssum1 = 0.f;

  if (deg <= 32) {
    int s = 0;
    float ex0 = 0.f, ex1 = 0.f, ex2 = 0.f, ex3 = 0.f;
    if (c < deg) {
      s = csr_src[start + c];
      float4 q = reinterpret_cast<const float4*>(als)[s];
      float v0 = q.x + adq.x, v1 = q.y + adq.y, v2 = q.z + adq.z, v3 = q.w + adq.w;
      v0 = v0 > 0.f ? v0 : 0.2f * v0; v1 = v1 > 0.f ? v1 : 0.2f * v1;
      v2 = v2 > 0.f ? v2 : 0.2f * v2; v3 = v3 > 0.f ? v3 : 0.2f * v3;
      ex0 = __expf(v0); ex1 = __expf(v1); ex2 = __expf(v2); ex3 = __expf(v3);
    }
    s_src[wid][hw][c] = s;
    s_w[wid][hw][c][0] = make_float2(ex0, ex2);
    s_w[wid][hw][c][1] = make_float2(ex1, ex3);

    float b0a = 0.f, b1a = 0.f, b2a = 0.f, b3a = 0.f;
    float sb0 = 0.f, sb1 = 0.f;
    int j = 0;
    for (; j + 2 <= deg; j += 2) {
      int sa = s_src[wid][hw][j];
      int sb = s_src[wid][hw][j + 1];
      uint2 ua = *reinterpret_cast<const uint2*>(&hb[(size_t)sa * 64 + 2 * c]);
      uint2 ub = *reinterpret_cast<const uint2*>(&hb[(size_t)sb * 64 + 2 * c]);
      float2 wa = s_w[wid][hw][j][hsel];
      float2 wb = s_w[wid][hw][j + 1][hsel];
      a0 = fmaf(wa.x, hlo(ua.x), a0); a1 = fmaf(wa.x, hlo(ua.y), a1);
      a2 = fmaf(wa.y, hhi(ua.x), a2); a3 = fmaf(wa.y, hhi(ua.y), a3);
      ssum0 += wa.x; ssum1 += wa.y;
      b0a = fmaf(wb.x, hlo(ub.x), b0a); b1a = fmaf(wb.x, hlo(ub.y), b1a);
      b2a = fmaf(wb.y, hhi(ub.x), b2a); b3a = fmaf(wb.y, hhi(ub.y), b3a);
      sb0 += wb.x; sb1 += wb.y;
    }
    if (j < deg) {
      int sa = s_src[wid][hw][j];
      uint2 ua = *reinterpret_cast<const uint2*>(&hb[(size_t)sa * 64 + 2 * c]);
      float2 wa = s_w[wid][hw][j][hsel];
      a0 = fmaf(wa.x, hlo(ua.x), a0); a1 = fmaf(wa.x, hlo(ua.y), a1);
      a2 = fmaf(wa.y, hhi(ua.x), a2); a3 = fmaf(wa.y, hhi(ua.y), a3);
      ssum0 += wa.x; ssum1 += wa.y;
    }
    a0 += b0a; a1 += b1a; a2 += b2a; a3 += b3a;
    ssum0 += sb0; ssum1 += sb1;
  } else {
    // chunked fallback (deg > 32: rare at avg degree 16)
    for (int eb = 0; eb < deg; eb += 32) {
      int s = 0;
      float ex0 = 0.f, ex1 = 0.f, ex2 = 0.f, ex3 = 0.f;
      if (eb + c < deg) {
        s = csr_src[start + eb + c];
        float4 q = reinterpret_cast<const float4*>(als)[s];
        float v0 = q.x + adq.x, v1 = q.y + adq.y, v2 = q.z + adq.z, v3 = q.w + adq.w;
        v0 = v0 > 0.f ? v0 : 0.2f * v0; v1 = v1 > 0.f ? v1 : 0.2f * v1;
        v2 = v2 > 0.f ? v2 : 0.2f * v2; v3 = v3 > 0.f ? v3 : 0.2f * v3;
        ex0 = __expf(v0); ex1 = __expf(v1); ex2 = __expf(v2); ex3 = __expf(v3);
      }
      s_src[wid][hw][c] = s;
      s_w[wid][hw][c][0] = make_float2(ex0, ex2);
      s_w[wid][hw][c][1] = make_float2(ex1, ex3);
      int cnt = deg - eb; if (cnt > 32) cnt = 32;
      for (int j = 0; j < cnt; ++j) {
        int sj = s_src[wid][hw][j];
        uint2 u = *reinterpret_cast<const uint2*>(&hb[(size_t)sj * 64 + 2 * c]);
        float2 w = s_w[wid][hw][j][hsel];
        a0 = fmaf(w.x, hlo(u.x), a0); a1 = fmaf(w.x, hlo(u.y), a1);
        a2 = fmaf(w.y, hhi(u.x), a2); a3 = fmaf(w.y, hhi(u.y), a3);
        ssum0 += w.x; ssum1 += w.y;
      }
    }
  }

  float2 blo = *reinterpret_cast<const float2*>(&bias[2 * c]);
  float2 bhi = *reinterpret_cast<const float2*>(&bias[2 * c + 64]);
  float is0 = 1.f / (ssum0 + 1e-16f), is1 = 1.f / (ssum1 + 1e-16f);
  float o0 = a0 * is0 + blo.x;
  float o1 = a1 * is0 + blo.y;
  float o2 = a2 * is1 + bhi.x;
  float o3 = a3 * is1 + bhi.y;
  float red = o0 + o1 + o2 + o3;
  float sq2 = o0 * o0 + o1 * o1 + o2 * o2 + o3 * o3;
#pragma unroll
  for (int m = 1; m < 32; m <<= 1) {
    red += __shfl_xor(red, m);
    sq2 += __shfl_xor(sq2, m);
  }
  float mu = red * (1.f / 128.f);
  float var = sq2 * (1.f / 128.f) - mu * mu;
  float rstd = rsqrtf(var + 1e-5f);
  float2 glo = *reinterpret_cast<const float2*>(&ln_g[2 * c]);
  float2 ghi = *reinterpret_cast<const float2*>(&ln_g[2 * c + 64]);
  float2 bl2 = *reinterpret_cast<const float2*>(&ln_b[2 * c]);
  float2 bh2 = *reinterpret_cast<const float2*>(&ln_b[2 * c + 64]);
  float2 ylo, yhi;
  ylo.x = eluf((o0 - mu) * rstd * glo.x + bl2.x);
  ylo.y = eluf((o1 - mu) * rstd * glo.y + bl2.y);
  yhi.x = eluf((o2 - mu) * rstd * ghi.x + bh2.x);
  yhi.y = eluf((o3 - mu) * rstd * ghi.y + bh2.y);

  if constexpr (!FUSE) {
    *reinterpret_cast<float2*>(&out[(size_t)node * 128 + 2 * c]) = ylo;
    *reinterpret_cast<float2*>(&out[(size_t)node * 128 + 64 + 2 * c]) = yhi;
  } else {
    // broadcast y through LDS (wave-synchronous within the half-wave)
    int nidx = (wid * 2 + hw) * 128;
    *reinterpret_cast<float2*>(&y_s[nidx + 2 * c]) = ylo;
    *reinterpret_cast<float2*>(&y_s[nidx + 64 + 2 * c]) = yhi;
    // h2[node][c] = y . W2[:,c] -- conflict-free (lane c hits bank c),
    // 4 independent accumulator chains.
    float ac0 = 0.f, ac1 = 0.f, ac2 = 0.f, ac3 = 0.f;
#pragma unroll
    for (int k = 0; k < 128; k += 4) {
      float4 yv = *reinterpret_cast<const float4*>(&y_s[nidx + k]);
      ac0 = fmaf(yv.x, w2s[(k + 0) * 32 + c], ac0);
      ac1 = fmaf(yv.y, w2s[(k + 1) * 32 + c], ac1);
      ac2 = fmaf(yv.z, w2s[(k + 2) * 32 + c], ac2);
      ac3 = fmaf(yv.w, w2s[(k + 3) * 32 + c], ac3);
    }
    float acc = (ac0 + ac1) + (ac2 + ac3);
    h2h[(size_t)node * 32 + c] = (unsigned short)(packh(acc, acc) & 0xffffu);
    float ps = acc * as2[c], pd = acc * ad2[c];
#pragma unroll
    for (int m = 1; m < 32; m <<= 1) { ps += __shfl_xor(ps, m); pd += __shfl_xor(pd, m); }
    if (c == 0) { als2[node] = ps; ald2[node] = pd; }
  }
}

// Aggregate for OUT=32 (fp16 h rows, 2B/feature). Half-wave per node.
__global__ __launch_bounds__(256) void aggregate32_kernel(
    const unsigned short* __restrict__ h, const float* __restrict__ als, const float* __restrict__ ald,
    const int* __restrict__ row_ptr, const int* __restrict__ csr_src,
    const float* __restrict__ bias, const float* __restrict__ ln_g, const float* __restrict__ ln_b,
    float* __restrict__ out, int n)
{
  __shared__ int s_src[4][2][32];
  __shared__ float s_ex[4][2][32];
  int t = threadIdx.x, lane = t & 63, wid = t >> 6;
  int hw = lane >> 5, c = lane & 31;
  int node = blockIdx.x * 8 + wid * 2 + hw;
  int start = row_ptr[node], end = row_ptr[node + 1];
  int deg = end - start;
  float adl = ald[node];
  float acc0 = 0.f, ssum = 0.f;

  if (deg <= 32) {
    int s = 0; float ex = 0.f;
    if (c < deg) {
      s = csr_src[start + c];
      float v = als[s] + adl;
      v = v > 0.f ? v : 0.2f * v;
      ex = __expf(v);
    }
    s_src[wid][hw][c] = s;
    s_ex[wid][hw][c] = ex;

    float acc1 = 0.f, ssum1 = 0.f;
    int j = 0;
    for (; j + 2 <= deg; j += 2) {
      int sa = s_src[wid][hw][j];
      int sb = s_src[wid][hw][j + 1];
      float ha = h16f(h[(size_t)sa * 32 + c]);
      float hbv = h16f(h[(size_t)sb * 32 + c]);
      float wa = s_ex[wid][hw][j];
      float wb = s_ex[wid][hw][j + 1];
      acc0 = fmaf(wa, ha, acc0); ssum += wa;
      acc1 = fmaf(wb, hbv, acc1); ssum1 += wb;
    }
    if (j < deg) {
      float wa = s_ex[wid][hw][j];
      acc0 = fmaf(wa, h16f(h[(size_t)s_src[wid][hw][j] * 32 + c]), acc0);
      ssum += wa;
    }
    acc0 += acc1; ssum += ssum1;
  } else {
    for (int eb = 0; eb < deg; eb += 32) {
      int s = 0; float ex = 0.f;
      if (eb + c < deg) {
        s = csr_src[start + eb + c];
        float v = als[s] + adl;
        v = v > 0.f ? v : 0.2f * v;
        ex = __expf(v);
      }
      s_src[wid][hw][c] = s;
      s_ex[wid][hw][c] = ex;
      int cnt = deg - eb; if (cnt > 32) cnt = 32;
      for (int j = 0; j < cnt; ++j) {
        float w = s_ex[wid][hw][j];
        acc0 = fmaf(w, h16f(h[(size_t)s_src[wid][hw][j] * 32 + c]), acc0);
        ssum += w;
      }
    }
  }

  float o0 = acc0 / (ssum + 1e-16f) + bias[c];
  float red = o0, sq2 = o0 * o0;
#pragma unroll
  for (int m = 1; m < 32; m <<= 1) {
    red += __shfl_xor(red, m);
    sq2 += __shfl_xor(sq2, m);
  }
  float mu = red * (1.f / 32.f);
  float var = sq2 * (1.f / 32.f) - mu * mu;
  float rstd = rsqrtf(var + 1e-5f);
  float y0 = (o0 - mu) * rstd * ln_g[c] + ln_b[c];
  out[(size_t)node * 32 + c] = eluf(y0);
}

__device__ __forceinline__ int lower_bound_dev(const int* a, int n, int key) {
  int lo = 0, hi = n;
  while (lo < hi) { int mid = (lo + hi) >> 1; if (a[mid] < key) lo = mid + 1; else hi = mid; }
  return lo;
}

// Fused global mean-pool + 2-layer classifier: one block per group.
__global__ __launch_bounds__(256) void poolfc_kernel(
    const float* __restrict__ x2, const int* __restrict__ batch,
    const float* __restrict__ fc1w, const float* __restrict__ fc1b,
    const float* __restrict__ fc2w, const float* __restrict__ fc2b,
    float* __restrict__ out, int n)
{
  int g = blockIdx.x;
  int lo = lower_bound_dev(batch, n, g);
  int hi = lower_bound_dev(batch, n, g + 1);
  int t = threadIdx.x;
  int c = t & 31, r = t >> 5;
  float acc = 0.f;
  for (int i = lo + r; i < hi; i += 8) acc += x2[(size_t)i * 32 + c];
  __shared__ float red[8][32];
  __shared__ float hgl[32];
  __shared__ float zl[16];
  red[r][c] = acc;
  __syncthreads();
  if (r == 0) {
    float s = 0.f;
#pragma unroll
    for (int k = 0; k < 8; ++k) s += red[k][c];
    float cnt = (float)(hi - lo);
    hgl[c] = s / fmaxf(cnt, 1.f);
  }
  __syncthreads();
  if (t < 16) {
    float a = fc1b[t];
#pragma unroll
    for (int k = 0; k < 32; ++k) a = fmaf(hgl[k], fc1w[k * 16 + t], a);
    zl[t] = fmaxf(a, 0.f);
  }
  __syncthreads();
  if (t < 2) {
    float a = fc2b[t];
#pragma unroll
    for (int j = 0; j < 16; ++j) a = fmaf(zl[j], fc2w[j * 2 + t], a);
    out[g * 2 + t] = a;
  }
}

extern "C" void kernel_launch(void* const* d_in, const int* in_sizes, int n_in,
                              void* d_out, int out_size, void* d_ws, size_t ws_size,
                              hipStream_t stream) {
  const float* x    = (const float*)d_in[0];
  const int*   ei   = (const int*)d_in[1];
  const int*   batch= (const int*)d_in[2];
  const float* W0   = (const float*)d_in[3];
  const float* as0  = (const float*)d_in[4];
  const float* ad0  = (const float*)d_in[5];
  const float* b0   = (const float*)d_in[6];
  const float* ln0g = (const float*)d_in[7];
  const float* ln0b = (const float*)d_in[8];
  const float* W1   = (const float*)d_in[9];
  const float* as1  = (const float*)d_in[10];
  const float* ad1  = (const float*)d_in[11];
  const float* b1   = (const float*)d_in[12];
  const float* ln1g = (const float*)d_in[13];
  const float* ln1b = (const float*)d_in[14];
  const float* W2   = (const float*)d_in[15];
  const float* as2  = (const float*)d_in[16];
  const float* ad2  = (const float*)d_in[17];
  const float* b2   = (const float*)d_in[18];
  const float* ln2g = (const float*)d_in[19];
  const float* ln2b = (const float*)d_in[20];
  const float* fc1w = (const float*)d_in[21];
  const float* fc1b = (const float*)d_in[22];
  const float* fc2w = (const float*)d_in[23];
  const float* fc2b = (const float*)d_in[24];
  float* out = (float*)d_out;

  const int* srce = ei;
  const int* dste = ei + EE;

  unsigned* hb = (unsigned*)d_ws;              // N*64 packed fp16 pairs
  float* B2  = (float*)(hb + (size_t)NN * 64); // N*128
  float* als = B2 + (size_t)NN * 128;          // N*4
  float* ald = als + (size_t)NN * 4;           // N*4
  unsigned short* h2h = (unsigned short*)(ald + (size_t)NN * 4); // N*32 fp16
  float* x2  = (float*)(h2h + (size_t)NN * 32);// N*32
  float* als2 = x2 + (size_t)NN * 32;          // N
  float* ald2 = als2 + NN;                     // N
  int* deg      = (int*)(ald2 + NN);           // N
  int* row_ptr  = deg + NN;                    // N+1
  int* cursor   = row_ptr + NN + 1;            // N
  int* csr_src  = cursor + NN;                 // E
  int* bsum     = csr_src + EE;                // SCAN_BLOCKS

  // CSR build (shared by all 3 layers)
  zero_int_kernel<<<(NN + 255) / 256, 256, 0, stream>>>(deg, NN);
  count_deg_kernel<<<(EE / 4 + 255) / 256, 256, 0, stream>>>(dste, deg, EE);
  scanA_kernel<<<SCAN_BLOCKS, 1024, 0, stream>>>(deg, row_ptr, bsum, NN);
  scanC_kernel<<<SCAN_BLOCKS, 1024, 0, stream>>>(row_ptr, bsum, cursor, NN);
  scatter_kernel<<<(EE / 4 + 255) / 256, 256, 0, stream>>>(srce, dste, cursor, csr_src, EE);

  // layer 0
  gemm128_kernel<<<625, 256, 0, stream>>>(x, W0, as0, ad0, hb, als, ald);
  aggregate128_kernel<false><<<NN / 8, 256, 0, stream>>>(hb, als, ald, row_ptr, csr_src,
                                                         b0, ln0g, ln0b, B2,
                                                         nullptr, nullptr, nullptr,
                                                         nullptr, nullptr, nullptr);
  // layer 1 (+ fused layer-2 GEMM and attention projections)
  gemm128_kernel<<<625, 256, 0, stream>>>(B2, W1, as1, ad1, hb, als, ald);
  aggregate128_kernel<true><<<NN / 8, 256, 0, stream>>>(hb, als, ald, row_ptr, csr_src,
                                                        b1, ln1g, ln1b, nullptr,
                                                        W2, as2, ad2, h2h, als2, ald2);
  // layer 2 aggregate
  aggregate32_kernel<<<NN / 8, 256, 0, stream>>>(h2h, als2, ald2, row_ptr, csr_src,
                                                 b2, ln2g, ln2b, x2, NN);
  // pool + classifier (fused)
  poolfc_kernel<<<NG, 256, 0, stream>>>(x2, batch, fc1w, fc1b, fc2w, fc2b, out, NN);
}

// Round 13
// 244.912 us; speedup vs baseline: 1.0478x; 1.0395x over previous
//
#include <hip/hip_runtime.h>
#include <hip/hip_fp16.h>
#include <math.h>

#define NN 40000
#define EE 640000
#define NG 64
#define SCAN_BLOCKS ((NN + 1023) / 1024)

__device__ __forceinline__ float eluf(float x) { return x > 0.f ? x : expm1f(x); }

typedef const __attribute__((address_space(1))) char gas_char;
typedef __attribute__((address_space(3))) char las_char;

__device__ __forceinline__ void async_copy16(void* l, const void* g) {
  __builtin_amdgcn_global_load_lds((gas_char*)g, (las_char*)l, 16, 0, 0);
}

typedef __fp16 f16x2 __attribute__((ext_vector_type(2)));
__device__ __forceinline__ unsigned packh(float lo, float hi) {  // f32x2 -> packed fp16
  f16x2 p = __builtin_amdgcn_cvt_pkrtz(lo, hi);
  union { f16x2 h; unsigned u; } c; c.h = p; return c.u;
}
__device__ __forceinline__ float hlo(unsigned p) {
  union { unsigned u; f16x2 h; } c; c.u = p; return (float)c.h.x;
}
__device__ __forceinline__ float hhi(unsigned p) {
  union { unsigned u; f16x2 h; } c; c.u = p; return (float)c.h.y;
}

__global__ void zero_int_kernel(int* __restrict__ p, int n) {
  int i = blockIdx.x * 256 + threadIdx.x;
  if (i < n) p[i] = 0;
}

// 4 edges/thread, int4 loads, 4 independent atomic chains.
__global__ void count_deg_kernel(const int* __restrict__ dst, int* __restrict__ deg, int e) {
  int i0 = (blockIdx.x * 256 + threadIdx.x) * 4;
  if (i0 + 4 <= e) {
    int4 d4 = *reinterpret_cast<const int4*>(&dst[i0]);
    atomicAdd(&deg[d4.x], 1);
    atomicAdd(&deg[d4.y], 1);
    atomicAdd(&deg[d4.z], 1);
    atomicAdd(&deg[d4.w], 1);
  } else {
    for (int i = i0; i < e; ++i) atomicAdd(&deg[dst[i]], 1);
  }
}

__global__ __launch_bounds__(1024) void scanA_kernel(const int* __restrict__ deg,
                                                     int* __restrict__ row_ptr,
                                                     int* __restrict__ bsum, int n) {
  __shared__ int wsum[16];
  int t = threadIdx.x, lane = t & 63, wid = t >> 6;
  int i = blockIdx.x * 1024 + t;
  int v = (i < n) ? deg[i] : 0;
#pragma unroll
  for (int off = 1; off < 64; off <<= 1) {
    int u = __shfl_up(v, off);
    if (lane >= off) v += u;
  }
  if (lane == 63) wsum[wid] = v;
  __syncthreads();
  if (t < 16) {
    int w = wsum[t];
#pragma unroll
    for (int off = 1; off < 16; off <<= 1) {
      int u = __shfl_up(w, off);
      if (t >= off) w += u;
    }
    wsum[t] = w;
  }
  __syncthreads();
  if (wid > 0) v += wsum[wid - 1];
  if (i < n) row_ptr[i + 1] = v;
  if (t == 1023) bsum[blockIdx.x] = v;
}

// scanC with inlined block-offset reduce (scanB merged).
__global__ __launch_bounds__(1024) void scanC_kernel(int* __restrict__ row_ptr,
                                                     const int* __restrict__ bsum,
                                                     int* __restrict__ cursor, int n) {
  __shared__ int off_s;
  int t = threadIdx.x;
  int b = blockIdx.x;
  if (t < 64) {
    int v = (t < b && t < SCAN_BLOCKS) ? bsum[t] : 0;
#pragma unroll
    for (int m = 1; m < 64; m <<= 1) v += __shfl_xor(v, m);
    if (t == 0) off_s = v;
  }
  __syncthreads();
  int off = off_s;
  int i = b * 1024 + t;
  if (i < n) {
    int v = row_ptr[i + 1] + off;
    row_ptr[i + 1] = v;
    if (i + 1 < n) cursor[i + 1] = v;
    if (i == 0) { cursor[0] = 0; row_ptr[0] = 0; }
  }
}

// 4 edges/thread: int4 loads of src/dst, 4 independent atomic->store chains.
__global__ void scatter_kernel(const int* __restrict__ src, const int* __restrict__ dst,
                               int* __restrict__ cursor, int* __restrict__ csr_src, int e) {
  int i0 = (blockIdx.x * 256 + threadIdx.x) * 4;
  if (i0 + 4 <= e) {
    int4 s4 = *reinterpret_cast<const int4*>(&src[i0]);
    int4 d4 = *reinterpret_cast<const int4*>(&dst[i0]);
    int p0 = atomicAdd(&cursor[d4.x], 1);
    int p1 = atomicAdd(&cursor[d4.y], 1);
    int p2 = atomicAdd(&cursor[d4.z], 1);
    int p3 = atomicAdd(&cursor[d4.w], 1);
    csr_src[p0] = s4.x;
    csr_src[p1] = s4.y;
    csr_src[p2] = s4.z;
    csr_src[p3] = s4.w;
  } else {
    for (int i = i0; i < e; ++i) {
      int d = dst[i];
      int pos = atomicAdd(&cursor[d], 1);
      csr_src[pos] = src[i];
    }
  }
}

// GEMM (K=128, OUT=128): h = x @ W written as PACKED FP16 pairs.
// LDS 48KB (x k-chunked dbuf 16KB + W dbuf 32KB) -> 3 blocks/CU.
__global__ __launch_bounds__(256, 3) void gemm128_kernel(
    const float* __restrict__ x, const float* __restrict__ W,
    const float* __restrict__ a_s, const float* __restrict__ a_d,
    unsigned* __restrict__ hb, float* __restrict__ als, float* __restrict__ ald)
{
  __shared__ float xs[2][64 * 32];
  __shared__ float ws[2][32 * 128];

  int t = threadIdx.x;
  int row0 = blockIdx.x * 64;
  const char* xgb = (const char*)x + (size_t)row0 * 512;

  {
    int li0 = t, li1 = t + 256;
    async_copy16((char*)xs[0] + li0 * 16, xgb + (li0 >> 3) * 512 + (li0 & 7) * 16);
    async_copy16((char*)xs[0] + li1 * 16, xgb + (li1 >> 3) * 512 + (li1 & 7) * 16);
    const char* wg = (const char*)W;
#pragma unroll
    for (int p = 0; p < 4; ++p)
      async_copy16((char*)ws[0] + p * 4096 + t * 16, wg + p * 4096 + t * 16);
  }
  __syncthreads();

  int cg = t & 31, rg = t >> 5;
  int r0 = rg * 8;
  int jlo = 2 * cg;

  float acc[8][4];
#pragma unroll
  for (int r = 0; r < 8; ++r)
#pragma unroll
    for (int c = 0; c < 4; ++c) acc[r][c] = 0.f;

  for (int ch = 0; ch < 4; ++ch) {
    if (ch < 3) {
      int b = (ch + 1) & 1;
      int li0 = t, li1 = t + 256;
      const char* xg = xgb + (ch + 1) * 128;
      async_copy16((char*)xs[b] + li0 * 16, xg + (li0 >> 3) * 512 + (li0 & 7) * 16);
      async_copy16((char*)xs[b] + li1 * 16, xg + (li1 >> 3) * 512 + (li1 & 7) * 16);
      const char* wg = (const char*)W + (size_t)(ch + 1) * 32 * 128 * 4;
#pragma unroll
      for (int p = 0; p < 4; ++p)
        async_copy16((char*)ws[b] + p * 4096 + t * 16, wg + p * 4096 + t * 16);
    }
    const float* wc = ws[ch & 1];
    const float* xc = xs[ch & 1];
#pragma unroll
    for (int kk = 0; kk < 32; kk += 4) {
      float2 wlo[4], whi[4];
#pragma unroll
      for (int q = 0; q < 4; ++q) {
        wlo[q] = *reinterpret_cast<const float2*>(&wc[(kk + q) * 128 + jlo]);
        whi[q] = *reinterpret_cast<const float2*>(&wc[(kk + q) * 128 + 64 + jlo]);
      }
#pragma unroll
      for (int r = 0; r < 8; ++r) {
        float4 xv = *reinterpret_cast<const float4*>(&xc[(r0 + r) * 32 + kk]);
        float a0 = acc[r][0], a1 = acc[r][1], a2 = acc[r][2], a3 = acc[r][3];
        a0 = fmaf(xv.x, wlo[0].x, a0); a1 = fmaf(xv.x, wlo[0].y, a1);
        a2 = fmaf(xv.x, whi[0].x, a2); a3 = fmaf(xv.x, whi[0].y, a3);
        a0 = fmaf(xv.y, wlo[1].x, a0); a1 = fmaf(xv.y, wlo[1].y, a1);
        a2 = fmaf(xv.y, whi[1].x, a2); a3 = fmaf(xv.y, whi[1].y, a3);
        a0 = fmaf(xv.z, wlo[2].x, a0); a1 = fmaf(xv.z, wlo[2].y, a1);
        a2 = fmaf(xv.z, whi[2].x, a2); a3 = fmaf(xv.z, whi[2].y, a3);
        a0 = fmaf(xv.w, wlo[3].x, a0); a1 = fmaf(xv.w, wlo[3].y, a1);
        a2 = fmaf(xv.w, whi[3].x, a2); a3 = fmaf(xv.w, whi[3].y, a3);
        acc[r][0] = a0; acc[r][1] = a1; acc[r][2] = a2; acc[r][3] = a3;
      }
    }
    __syncthreads();
  }

#pragma unroll
  for (int r = 0; r < 8; ++r) {
    uint2 pv;
    pv.x = packh(acc[r][0], acc[r][2]);
    pv.y = packh(acc[r][1], acc[r][3]);
    *reinterpret_cast<uint2*>(&hb[(size_t)(row0 + r0 + r) * 64 + jlo]) = pv;
  }

  float as0 = a_s[jlo], as1 = a_s[jlo + 1], as2 = a_s[jlo + 64], as3 = a_s[jlo + 65];
  float ad0 = a_d[jlo], ad1 = a_d[jlo + 1], ad2 = a_d[jlo + 64], ad3 = a_d[jlo + 65];
  int lane = t & 63;
#pragma unroll
  for (int r = 0; r < 8; ++r) {
    float psa = fmaf(acc[r][0], as0, acc[r][1] * as1);
    float psb = fmaf(acc[r][2], as2, acc[r][3] * as3);
    float pda = fmaf(acc[r][0], ad0, acc[r][1] * ad1);
    float pdb = fmaf(acc[r][2], ad2, acc[r][3] * ad3);
#pragma unroll
    for (int m = 1; m < 16; m <<= 1) {
      psa += __shfl_xor(psa, m); psb += __shfl_xor(psb, m);
      pda += __shfl_xor(pda, m); pdb += __shfl_xor(pdb, m);
    }
    if ((lane & 15) == 0) {
      int hA = (lane >> 4) & 1;
      size_t row = (size_t)(row0 + r0 + r);
      als[row * 4 + hA] = psa; als[row * 4 + hA + 2] = psb;
      ald[row * 4 + hA] = pda; ald[row * 4 + hA + 2] = pdb;
    }
  }
}

// Aggregate for OUT=128, QUARTER-WAVE per node: 16 nodes per 256-thread block.
// Lane c4 (=lane&15) owns features {4c4..4c4+3, 64+4c4..64+4c4+3} via ONE
// uint4 load per edge (4 nodes advance per wave-instruction). Uniform
// 16-edge-chunk staging (no deg special case); ssum per-lane (no reduce);
// LN reduces over 16 lanes (4 shfl steps). LDS padded to stride 17 / 132 so
// the 4 quarter-groups hit distinct banks.
template<bool FUSE>
__global__ __launch_bounds__(256) void aggregate128_kernel(
    const unsigned* __restrict__ hb, const float* __restrict__ als, const float* __restrict__ ald,
    const int* __restrict__ row_ptr, const int* __restrict__ csr_src,
    const float* __restrict__ bias, const float* __restrict__ ln_g, const float* __restrict__ ln_b,
    float* __restrict__ out,
    const float* __restrict__ W2, const float* __restrict__ as2, const float* __restrict__ ad2,
    unsigned short* __restrict__ h2h, float* __restrict__ als2, float* __restrict__ ald2)
{
  __shared__ int s_src[4][4][17];
  __shared__ float2 s_w[4][4][17][2];
  __shared__ __align__(16) float w2s[FUSE ? 32 * 128 : 4];
  __shared__ __align__(16) float y_s[FUSE ? 16 * 132 : 4];

  int t = threadIdx.x, lane = t & 63, wid = t >> 6;
  int q = lane >> 4, c4 = lane & 15;
  int node = blockIdx.x * 16 + wid * 4 + q;   // N = 40000 = 2500*16 exact

  if constexpr (FUSE) {
#pragma unroll
    for (int p = 0; p < 4; ++p)
      async_copy16((char*)w2s + p * 4096 + t * 16, (const char*)W2 + p * 4096 + t * 16);
    __syncthreads();
  }

  int start = row_ptr[node], end = row_ptr[node + 1];
  int deg = end - start;

  float4 adq = reinterpret_cast<const float4*>(ald)[node];
  int hsel = c4 >> 3;                 // head pair (hsel, hsel+2)
  const uint4* hbase = reinterpret_cast<const uint4*>(hb + 4 * c4);
  float a0 = 0.f, a1 = 0.f, a2 = 0.f, a3 = 0.f;     // features 4c4..4c4+3
  float a4 = 0.f, a5 = 0.f, a6 = 0.f, a7 = 0.f;     // features 64+4c4..+3
  float b0 = 0.f, b1 = 0.f, b2 = 0.f, b3 = 0.f;
  float b4 = 0.f, b5 = 0.f, b6 = 0.f, b7 = 0.f;
  float ssum0 = 0.f, ssum1 = 0.f, sb0 = 0.f, sb1 = 0.f;

  for (int eb = 0; eb < deg; eb += 16) {
    int s = 0;
    float ex0 = 0.f, ex1 = 0.f, ex2 = 0.f, ex3 = 0.f;
    if (eb + c4 < deg) {
      s = csr_src[start + eb + c4];
      float4 qv = reinterpret_cast<const float4*>(als)[s];
      float v0 = qv.x + adq.x, v1 = qv.y + adq.y, v2 = qv.z + adq.z, v3 = qv.w + adq.w;
      v0 = v0 > 0.f ? v0 : 0.2f * v0; v1 = v1 > 0.f ? v1 : 0.2f * v1;
      v2 = v2 > 0.f ? v2 : 0.2f * v2; v3 = v3 > 0.f ? v3 : 0.2f * v3;
      ex0 = __expf(v0); ex1 = __expf(v1); ex2 = __expf(v2); ex3 = __expf(v3);
    }
    s_src[wid][q][c4] = s;
    s_w[wid][q][c4][0] = make_float2(ex0, ex2);
    s_w[wid][q][c4][1] = make_float2(ex1, ex3);

    int cnt = deg - eb; if (cnt > 16) cnt = 16;
    int j = 0;
    for (; j + 2 <= cnt; j += 2) {
      int sa = s_src[wid][q][j];
      int sb = s_src[wid][q][j + 1];
      uint4 ua = hbase[(size_t)sa * 16];
      uint4 ub = hbase[(size_t)sb * 16];
      float2 wa = s_w[wid][q][j][hsel];
      float2 wb = s_w[wid][q][j + 1][hsel];
      a0 = fmaf(wa.x, hlo(ua.x), a0); a1 = fmaf(wa.x, hlo(ua.y), a1);
      a2 = fmaf(wa.x, hlo(ua.z), a2); a3 = fmaf(wa.x, hlo(ua.w), a3);
      a4 = fmaf(wa.y, hhi(ua.x), a4); a5 = fmaf(wa.y, hhi(ua.y), a5);
      a6 = fmaf(wa.y, hhi(ua.z), a6); a7 = fmaf(wa.y, hhi(ua.w), a7);
      ssum0 += wa.x; ssum1 += wa.y;
      b0 = fmaf(wb.x, hlo(ub.x), b0); b1 = fmaf(wb.x, hlo(ub.y), b1);
      b2 = fmaf(wb.x, hlo(ub.z), b2); b3 = fmaf(wb.x, hlo(ub.w), b3);
      b4 = fmaf(wb.y, hhi(ub.x), b4); b5 = fmaf(wb.y, hhi(ub.y), b5);
      b6 = fmaf(wb.y, hhi(ub.z), b6); b7 = fmaf(wb.y, hhi(ub.w), b7);
      sb0 += wb.x; sb1 += wb.y;
    }
    if (j < cnt) {
      int sa = s_src[wid][q][j];
      uint4 ua = hbase[(size_t)sa * 16];
      float2 wa = s_w[wid][q][j][hsel];
      a0 = fmaf(wa.x, hlo(ua.x), a0); a1 = fmaf(wa.x, hlo(ua.y), a1);
      a2 = fmaf(wa.x, hlo(ua.z), a2); a3 = fmaf(wa.x, hlo(ua.w), a3);
      a4 = fmaf(wa.y, hhi(ua.x), a4); a5 = fmaf(wa.y, hhi(ua.y), a5);
      a6 = fmaf(wa.y, hhi(ua.z), a6); a7 = fmaf(wa.y, hhi(ua.w), a7);
      ssum0 += wa.x; ssum1 += wa.y;
    }
  }
  a0 += b0; a1 += b1; a2 += b2; a3 += b3;
  a4 += b4; a5 += b5; a6 += b6; a7 += b7;
  ssum0 += sb0; ssum1 += sb1;

  float4 blo = *reinterpret_cast<const float4*>(&bias[4 * c4]);
  float4 bhi = *reinterpret_cast<const float4*>(&bias[64 + 4 * c4]);
  float is0 = 1.f / (ssum0 + 1e-16f), is1 = 1.f / (ssum1 + 1e-16f);
  float o0 = a0 * is0 + blo.x, o1 = a1 * is0 + blo.y;
  float o2 = a2 * is0 + blo.z, o3 = a3 * is0 + blo.w;
  float o4 = a4 * is1 + bhi.x, o5 = a5 * is1 + bhi.y;
  float o6 = a6 * is1 + bhi.z, o7 = a7 * is1 + bhi.w;
  float red = (o0 + o1 + o2 + o3) + (o4 + o5 + o6 + o7);
  float sq2 = (o0 * o0 + o1 * o1 + o2 * o2 + o3 * o3)
            + (o4 * o4 + o5 * o5 + o6 * o6 + o7 * o7);
#pragma unroll
  for (int m = 1; m < 16; m <<= 1) {
    red += __shfl_xor(red, m);
    sq2 += __shfl_xor(sq2, m);
  }
  float mu = red * (1.f / 128.f);
  float var = sq2 * (1.f / 128.f) - mu * mu;
  float rstd = rsqrtf(var + 1e-5f);
  float4 glo = *reinterpret_cast<const float4*>(&ln_g[4 * c4]);
  float4 ghi = *reinterpret_cast<const float4*>(&ln_g[64 + 4 * c4]);
  float4 bl2 = *reinterpret_cast<const float4*>(&ln_b[4 * c4]);
  float4 bh2 = *reinterpret_cast<const float4*>(&ln_b[64 + 4 * c4]);
  float4 ylo, yhi;
  ylo.x = eluf((o0 - mu) * rstd * glo.x + bl2.x);
  ylo.y = eluf((o1 - mu) * rstd * glo.y + bl2.y);
  ylo.z = eluf((o2 - mu) * rstd * glo.z + bl2.z);
  ylo.w = eluf((o3 - mu) * rstd * glo.w + bl2.w);
  yhi.x = eluf((o4 - mu) * rstd * ghi.x + bh2.x);
  yhi.y = eluf((o5 - mu) * rstd * ghi.y + bh2.y);
  yhi.z = eluf((o6 - mu) * rstd * ghi.z + bh2.z);
  yhi.w = eluf((o7 - mu) * rstd * ghi.w + bh2.w);

  if constexpr (!FUSE) {
    *reinterpret_cast<float4*>(&out[(size_t)node * 128 + 4 * c4]) = ylo;
    *reinterpret_cast<float4*>(&out[(size_t)node * 128 + 64 + 4 * c4]) = yhi;
  } else {
    // broadcast y through LDS (row stride 132 -> quarter-groups on distinct banks)
    int nidx = (wid * 4 + q) * 132;
    *reinterpret_cast<float4*>(&y_s[nidx + 4 * c4]) = ylo;
    *reinterpret_cast<float4*>(&y_s[nidx + 64 + 4 * c4]) = yhi;
    // lane computes h2 cols c4 and c4+16; w2s[k*32+col]: bank==col, broadcast x4.
    float d0 = 0.f, d1 = 0.f, d2 = 0.f, d3 = 0.f;
#pragma unroll
    for (int k = 0; k < 128; k += 2) {
      float2 yv = *reinterpret_cast<const float2*>(&y_s[nidx + k]);
      d0 = fmaf(yv.x, w2s[k * 32 + c4], d0);
      d1 = fmaf(yv.y, w2s[(k + 1) * 32 + c4], d1);
      d2 = fmaf(yv.x, w2s[k * 32 + c4 + 16], d2);
      d3 = fmaf(yv.y, w2s[(k + 1) * 32 + c4 + 16], d3);
    }
    float accA = d0 + d1, accB = d2 + d3;
    unsigned pa = packh(accA, accB);
    h2h[(size_t)node * 32 + c4] = (unsigned short)(pa & 0xffffu);
    h2h[(size_t)node * 32 + c4 + 16] = (unsigned short)(pa >> 16);
    float ps = fmaf(accA, as2[c4], accB * as2[c4 + 16]);
    float pd = fmaf(accA, ad2[c4], accB * ad2[c4 + 16]);
#pragma unroll
    for (int m = 1; m < 16; m <<= 1) { ps += __shfl_xor(ps, m); pd += __shfl_xor(pd, m); }
    if (c4 == 0) { als2[node] = ps; ald2[node] = pd; }
  }
}

// Aggregate for OUT=32 (fp16 rows). QUARTER-WAVE per node; lane c4 owns
// features {2c4, 2c4+1} via one u32 load per edge.
__global__ __launch_bounds__(256) void aggregate32_kernel(
    const unsigned short* __restrict__ h, const float* __restrict__ als, const float* __restrict__ ald,
    const int* __restrict__ row_ptr, const int* __restrict__ csr_src,
    const float* __restrict__ bias, const float* __restrict__ ln_g, const float* __restrict__ ln_b,
    float* __restrict__ out, int n)
{
  __shared__ int s_src[4][4][17];
  __shared__ float s_ex[4][4][17];
  int t = threadIdx.x, lane = t & 63, wid = t >> 6;
  int q = lane >> 4, c4 = lane & 15;
  int node = blockIdx.x * 16 + wid * 4 + q;
  int start = row_ptr[node], end = row_ptr[node + 1];
  int deg = end - start;
  float adl = ald[node];
  const unsigned* hu = reinterpret_cast<const unsigned*>(h);
  float acc0 = 0.f, acc1 = 0.f, bc0 = 0.f, bc1 = 0.f;
  float ssum = 0.f, sb = 0.f;

  for (int eb = 0; eb < deg; eb += 16) {
    int s = 0; float ex = 0.f;
    if (eb + c4 < deg) {
      s = csr_src[start + eb + c4];
      float v = als[s] + adl;
      v = v > 0.f ? v : 0.2f * v;
      ex = __expf(v);
    }
    s_src[wid][q][c4] = s;
    s_ex[wid][q][c4] = ex;

    int cnt = deg - eb; if (cnt > 16) cnt = 16;
    int j = 0;
    for (; j + 2 <= cnt; j += 2) {
      int sa = s_src[wid][q][j];
      int sbx = s_src[wid][q][j + 1];
      unsigned ua = hu[(size_t)sa * 16 + c4];
      unsigned ub = hu[(size_t)sbx * 16 + c4];
      float wa = s_ex[wid][q][j];
      float wb = s_ex[wid][q][j + 1];
      acc0 = fmaf(wa, hlo(ua), acc0); acc1 = fmaf(wa, hhi(ua), acc1); ssum += wa;
      bc0 = fmaf(wb, hlo(ub), bc0); bc1 = fmaf(wb, hhi(ub), bc1); sb += wb;
    }
    if (j < cnt) {
      int sa = s_src[wid][q][j];
      unsigned ua = hu[(size_t)sa * 16 + c4];
      float wa = s_ex[wid][q][j];
      acc0 = fmaf(wa, hlo(ua), acc0); acc1 = fmaf(wa, hhi(ua), acc1); ssum += wa;
    }
  }
  acc0 += bc0; acc1 += bc1; ssum += sb;

  float2 bv = *reinterpret_cast<const float2*>(&bias[2 * c4]);
  float is = 1.f / (ssum + 1e-16f);
  float o0 = acc0 * is + bv.x;
  float o1 = acc1 * is + bv.y;
  float red = o0 + o1, sq2 = o0 * o0 + o1 * o1;
#pragma unroll
  for (int m = 1; m < 16; m <<= 1) {
    red += __shfl_xor(red, m);
    sq2 += __shfl_xor(sq2, m);
  }
  float mu = red * (1.f / 32.f);
  float var = sq2 * (1.f / 32.f) - mu * mu;
  float rstd = rsqrtf(var + 1e-5f);
  float2 gv = *reinterpret_cast<const float2*>(&ln_g[2 * c4]);
  float2 lb = *reinterpret_cast<const float2*>(&ln_b[2 * c4]);
  float2 yv;
  yv.x = eluf((o0 - mu) * rstd * gv.x + lb.x);
  yv.y = eluf((o1 - mu) * rstd * gv.y + lb.y);
  *reinterpret_cast<float2*>(&out[(size_t)node * 32 + 2 * c4]) = yv;
}

__device__ __forceinline__ int lower_bound_dev(const int* a, int n, int key) {
  int lo = 0, hi = n;
  while (lo < hi) { int mid = (lo + hi) >> 1; if (a[mid] < key) lo = mid + 1; else hi = mid; }
  return lo;
}

// Fused global mean-pool + 2-layer classifier: one block per group.
__global__ __launch_bounds__(256) void poolfc_kernel(
    const float* __restrict__ x2, const int* __restrict__ batch,
    const float* __restrict__ fc1w, const float* __restrict__ fc1b,
    const float* __restrict__ fc2w, const float* __restrict__ fc2b,
    float* __restrict__ out, int n)
{
  int g = blockIdx.x;
  int lo = lower_bound_dev(batch, n, g);
  int hi = lower_bound_dev(batch, n, g + 1);
  int t = threadIdx.x;
  int c = t & 31, r = t >> 5;
  float acc = 0.f;
  for (int i = lo + r; i < hi; i += 8) acc += x2[(size_t)i * 32 + c];
  __shared__ float red[8][32];
  __shared__ float hgl[32];
  __shared__ float zl[16];
  red[r][c] = acc;
  __syncthreads();
  if (r == 0) {
    float s = 0.f;
#pragma unroll
    for (int k = 0; k < 8; ++k) s += red[k][c];
    float cnt = (float)(hi - lo);
    hgl[c] = s / fmaxf(cnt, 1.f);
  }
  __syncthreads();
  if (t < 16) {
    float a = fc1b[t];
#pragma unroll
    for (int k = 0; k < 32; ++k) a = fmaf(hgl[k], fc1w[k * 16 + t], a);
    zl[t] = fmaxf(a, 0.f);
  }
  __syncthreads();
  if (t < 2) {
    float a = fc2b[t];
#pragma unroll
    for (int j = 0; j < 16; ++j) a = fmaf(zl[j], fc2w[j * 2 + t], a);
    out[g * 2 + t] = a;
  }
}

extern "C" void kernel_launch(void* const* d_in, const int* in_sizes, int n_in,
                              void* d_out, int out_size, void* d_ws, size_t ws_size,
                              hipStream_t stream) {
  const float* x    = (const float*)d_in[0];
  const int*   ei   = (const int*)d_in[1];
  const int*   batch= (const int*)d_in[2];
  const float* W0   = (const float*)d_in[3];
  const float* as0  = (const float*)d_in[4];
  const float* ad0  = (const float*)d_in[5];
  const float* b0   = (const float*)d_in[6];
  const float* ln0g = (const float*)d_in[7];
  const float* ln0b = (const float*)d_in[8];
  const float* W1   = (const float*)d_in[9];
  const float* as1  = (const float*)d_in[10];
  const float* ad1  = (const float*)d_in[11];
  const float* b1   = (const float*)d_in[12];
  const float* ln1g = (const float*)d_in[13];
  const float* ln1b = (const float*)d_in[14];
  const float* W2   = (const float*)d_in[15];
  const float* as2  = (const float*)d_in[16];
  const float* ad2  = (const float*)d_in[17];
  const float* b2   = (const float*)d_in[18];
  const float* ln2g = (const float*)d_in[19];
  const float* ln2b = (const float*)d_in[20];
  const float* fc1w = (const float*)d_in[21];
  const float* fc1b = (const float*)d_in[22];
  const float* fc2w = (const float*)d_in[23];
  const float* fc2b = (const float*)d_in[24];
  float* out = (float*)d_out;

  const int* srce = ei;
  const int* dste = ei + EE;

  unsigned* hb = (unsigned*)d_ws;              // N*64 packed fp16 pairs
  float* B2  = (float*)(hb + (size_t)NN * 64); // N*128
  float* als = B2 + (size_t)NN * 128;          // N*4
  float* ald = als + (size_t)NN * 4;           // N*4
  unsigned short* h2h = (unsigned short*)(ald + (size_t)NN * 4); // N*32 fp16
  float* x2  = (float*)(h2h + (size_t)NN * 32);// N*32
  float* als2 = x2 + (size_t)NN * 32;          // N
  float* ald2 = als2 + NN;                     // N
  int* deg      = (int*)(ald2 + NN);           // N
  int* row_ptr  = deg + NN;                    // N+1
  int* cursor   = row_ptr + NN + 1;            // N
  int* csr_src  = cursor + NN;                 // E
  int* bsum     = csr_src + EE;                // SCAN_BLOCKS

  // CSR build (shared by all 3 layers)
  zero_int_kernel<<<(NN + 255) / 256, 256, 0, stream>>>(deg, NN);
  count_deg_kernel<<<(EE / 4 + 255) / 256, 256, 0, stream>>>(dste, deg, EE);
  scanA_kernel<<<SCAN_BLOCKS, 1024, 0, stream>>>(deg, row_ptr, bsum, NN);
  scanC_kernel<<<SCAN_BLOCKS, 1024, 0, stream>>>(row_ptr, bsum, cursor, NN);
  scatter_kernel<<<(EE / 4 + 255) / 256, 256, 0, stream>>>(srce, dste, cursor, csr_src, EE);

  // layer 0
  gemm128_kernel<<<625, 256, 0, stream>>>(x, W0, as0, ad0, hb, als, ald);
  aggregate128_kernel<false><<<NN / 16, 256, 0, stream>>>(hb, als, ald, row_ptr, csr_src,
                                                          b0, ln0g, ln0b, B2,
                                                          nullptr, nullptr, nullptr,
                                                          nullptr, nullptr, nullptr);
  // layer 1 (+ fused layer-2 GEMM and attention projections)
  gemm128_kernel<<<625, 256, 0, stream>>>(B2, W1, as1, ad1, hb, als, ald);
  aggregate128_kernel<true><<<NN / 16, 256, 0, stream>>>(hb, als, ald, row_ptr, csr_src,
                                                         b1, ln1g, ln1b, nullptr,
                                                         W2, as2, ad2, h2h, als2, ald2);
  // layer 2 aggregate
  aggregate32_kernel<<<NN / 16, 256, 0, stream>>>(h2h, als2, ald2, row_ptr, csr_src,
                                                  b2, ln2g, ln2b, x2, NN);
  // pool + classifier (fused)
  poolfc_kernel<<<NG, 256, 0, stream>>>(x2, batch, fc1w, fc1b, fc2w, fc2b, out, NN);
}

// Round 14
// 244.632 us; speedup vs baseline: 1.0490x; 1.0011x over previous
//
#include <hip/hip_runtime.h>
#include <hip/hip_fp16.h>
#include <math.h>

#define NN 40000
#define EE 640000
#define NG 64
#define SCAN_BLOCKS ((NN + 1023) / 1024)

__device__ __forceinline__ float eluf(float x) { return x > 0.f ? x : expm1f(x); }

typedef const __attribute__((address_space(1))) char gas_char;
typedef __attribute__((address_space(3))) char las_char;

__device__ __forceinline__ void async_copy16(void* l, const void* g) {
  __builtin_amdgcn_global_load_lds((gas_char*)g, (las_char*)l, 16, 0, 0);
}

typedef __fp16 f16x2 __attribute__((ext_vector_type(2)));
__device__ __forceinline__ unsigned packh(float lo, float hi) {  // f32x2 -> packed fp16
  f16x2 p = __builtin_amdgcn_cvt_pkrtz(lo, hi);
  union { f16x2 h; unsigned u; } c; c.h = p; return c.u;
}
__device__ __forceinline__ float hlo(unsigned p) {
  union { unsigned u; f16x2 h; } c; c.u = p; return (float)c.h.x;
}
__device__ __forceinline__ float hhi(unsigned p) {
  union { unsigned u; f16x2 h; } c; c.u = p; return (float)c.h.y;
}

__global__ void zero_int_kernel(int* __restrict__ p, int n) {
  int i = blockIdx.x * 256 + threadIdx.x;
  if (i < n) p[i] = 0;
}

// 2 edges/thread (ILP2) x 1250 blocks (high TLP).
__global__ void count_deg_kernel(const int* __restrict__ dst, int* __restrict__ deg, int e) {
  int i0 = (blockIdx.x * 256 + threadIdx.x) * 2;
  if (i0 + 2 <= e) {
    int2 d2 = *reinterpret_cast<const int2*>(&dst[i0]);
    atomicAdd(&deg[d2.x], 1);
    atomicAdd(&deg[d2.y], 1);
  } else {
    for (int i = i0; i < e; ++i) atomicAdd(&deg[dst[i]], 1);
  }
}

__global__ __launch_bounds__(1024) void scanA_kernel(const int* __restrict__ deg,
                                                     int* __restrict__ row_ptr,
                                                     int* __restrict__ bsum, int n) {
  __shared__ int wsum[16];
  int t = threadIdx.x, lane = t & 63, wid = t >> 6;
  int i = blockIdx.x * 1024 + t;
  int v = (i < n) ? deg[i] : 0;
#pragma unroll
  for (int off = 1; off < 64; off <<= 1) {
    int u = __shfl_up(v, off);
    if (lane >= off) v += u;
  }
  if (lane == 63) wsum[wid] = v;
  __syncthreads();
  if (t < 16) {
    int w = wsum[t];
#pragma unroll
    for (int off = 1; off < 16; off <<= 1) {
      int u = __shfl_up(w, off);
      if (t >= off) w += u;
    }
    wsum[t] = w;
  }
  __syncthreads();
  if (wid > 0) v += wsum[wid - 1];
  if (i < n) row_ptr[i + 1] = v;
  if (t == 1023) bsum[blockIdx.x] = v;
}

// scanC with inlined block-offset reduce (scanB merged).
__global__ __launch_bounds__(1024) void scanC_kernel(int* __restrict__ row_ptr,
                                                     const int* __restrict__ bsum,
                                                     int* __restrict__ cursor, int n) {
  __shared__ int off_s;
  int t = threadIdx.x;
  int b = blockIdx.x;
  if (t < 64) {
    int v = (t < b && t < SCAN_BLOCKS) ? bsum[t] : 0;
#pragma unroll
    for (int m = 1; m < 64; m <<= 1) v += __shfl_xor(v, m);
    if (t == 0) off_s = v;
  }
  __syncthreads();
  int off = off_s;
  int i = b * 1024 + t;
  if (i < n) {
    int v = row_ptr[i + 1] + off;
    row_ptr[i + 1] = v;
    if (i + 1 < n) cursor[i + 1] = v;
    if (i == 0) { cursor[0] = 0; row_ptr[0] = 0; }
  }
}

// 2 edges/thread (2 independent atomic->store chains) x 1250 blocks.
__global__ void scatter_kernel(const int* __restrict__ src, const int* __restrict__ dst,
                               int* __restrict__ cursor, int* __restrict__ csr_src, int e) {
  int i0 = (blockIdx.x * 256 + threadIdx.x) * 2;
  if (i0 + 2 <= e) {
    int2 s2 = *reinterpret_cast<const int2*>(&src[i0]);
    int2 d2 = *reinterpret_cast<const int2*>(&dst[i0]);
    int p0 = atomicAdd(&cursor[d2.x], 1);
    int p1 = atomicAdd(&cursor[d2.y], 1);
    csr_src[p0] = s2.x;
    csr_src[p1] = s2.y;
  } else {
    for (int i = i0; i < e; ++i) {
      int d = dst[i];
      int pos = atomicAdd(&cursor[d], 1);
      csr_src[pos] = src[i];
    }
  }
}

// GEMM (K=128, OUT=128): h = x @ W written as PACKED FP16 pairs.
// LDS 48KB (x k-chunked dbuf 16KB + W dbuf 32KB) -> 3 blocks/CU.
__global__ __launch_bounds__(256, 3) void gemm128_kernel(
    const float* __restrict__ x, const float* __restrict__ W,
    const float* __restrict__ a_s, const float* __restrict__ a_d,
    unsigned* __restrict__ hb, float* __restrict__ als, float* __restrict__ ald)
{
  __shared__ float xs[2][64 * 32];
  __shared__ float ws[2][32 * 128];

  int t = threadIdx.x;
  int row0 = blockIdx.x * 64;
  const char* xgb = (const char*)x + (size_t)row0 * 512;

  {
    int li0 = t, li1 = t + 256;
    async_copy16((char*)xs[0] + li0 * 16, xgb + (li0 >> 3) * 512 + (li0 & 7) * 16);
    async_copy16((char*)xs[0] + li1 * 16, xgb + (li1 >> 3) * 512 + (li1 & 7) * 16);
    const char* wg = (const char*)W;
#pragma unroll
    for (int p = 0; p < 4; ++p)
      async_copy16((char*)ws[0] + p * 4096 + t * 16, wg + p * 4096 + t * 16);
  }
  __syncthreads();

  int cg = t & 31, rg = t >> 5;
  int r0 = rg * 8;
  int jlo = 2 * cg;

  float acc[8][4];
#pragma unroll
  for (int r = 0; r < 8; ++r)
#pragma unroll
    for (int c = 0; c < 4; ++c) acc[r][c] = 0.f;

  for (int ch = 0; ch < 4; ++ch) {
    if (ch < 3) {
      int b = (ch + 1) & 1;
      int li0 = t, li1 = t + 256;
      const char* xg = xgb + (ch + 1) * 128;
      async_copy16((char*)xs[b] + li0 * 16, xg + (li0 >> 3) * 512 + (li0 & 7) * 16);
      async_copy16((char*)xs[b] + li1 * 16, xg + (li1 >> 3) * 512 + (li1 & 7) * 16);
      const char* wg = (const char*)W + (size_t)(ch + 1) * 32 * 128 * 4;
#pragma unroll
      for (int p = 0; p < 4; ++p)
        async_copy16((char*)ws[b] + p * 4096 + t * 16, wg + p * 4096 + t * 16);
    }
    const float* wc = ws[ch & 1];
    const float* xc = xs[ch & 1];
#pragma unroll
    for (int kk = 0; kk < 32; kk += 4) {
      float2 wlo[4], whi[4];
#pragma unroll
      for (int q = 0; q < 4; ++q) {
        wlo[q] = *reinterpret_cast<const float2*>(&wc[(kk + q) * 128 + jlo]);
        whi[q] = *reinterpret_cast<const float2*>(&wc[(kk + q) * 128 + 64 + jlo]);
      }
#pragma unroll
      for (int r = 0; r < 8; ++r) {
        float4 xv = *reinterpret_cast<const float4*>(&xc[(r0 + r) * 32 + kk]);
        float a0 = acc[r][0], a1 = acc[r][1], a2 = acc[r][2], a3 = acc[r][3];
        a0 = fmaf(xv.x, wlo[0].x, a0); a1 = fmaf(xv.x, wlo[0].y, a1);
        a2 = fmaf(xv.x, whi[0].x, a2); a3 = fmaf(xv.x, whi[0].y, a3);
        a0 = fmaf(xv.y, wlo[1].x, a0); a1 = fmaf(xv.y, wlo[1].y, a1);
        a2 = fmaf(xv.y, whi[1].x, a2); a3 = fmaf(xv.y, whi[1].y, a3);
        a0 = fmaf(xv.z, wlo[2].x, a0); a1 = fmaf(xv.z, wlo[2].y, a1);
        a2 = fmaf(xv.z, whi[2].x, a2); a3 = fmaf(xv.z, whi[2].y, a3);
        a0 = fmaf(xv.w, wlo[3].x, a0); a1 = fmaf(xv.w, wlo[3].y, a1);
        a2 = fmaf(xv.w, whi[3].x, a2); a3 = fmaf(xv.w, whi[3].y, a3);
        acc[r][0] = a0; acc[r][1] = a1; acc[r][2] = a2; acc[r][3] = a3;
      }
    }
    __syncthreads();
  }

#pragma unroll
  for (int r = 0; r < 8; ++r) {
    uint2 pv;
    pv.x = packh(acc[r][0], acc[r][2]);
    pv.y = packh(acc[r][1], acc[r][3]);
    *reinterpret_cast<uint2*>(&hb[(size_t)(row0 + r0 + r) * 64 + jlo]) = pv;
  }

  float as0 = a_s[jlo], as1 = a_s[jlo + 1], as2 = a_s[jlo + 64], as3 = a_s[jlo + 65];
  float ad0 = a_d[jlo], ad1 = a_d[jlo + 1], ad2 = a_d[jlo + 64], ad3 = a_d[jlo + 65];
  int lane = t & 63;
#pragma unroll
  for (int r = 0; r < 8; ++r) {
    float psa = fmaf(acc[r][0], as0, acc[r][1] * as1);
    float psb = fmaf(acc[r][2], as2, acc[r][3] * as3);
    float pda = fmaf(acc[r][0], ad0, acc[r][1] * ad1);
    float pdb = fmaf(acc[r][2], ad2, acc[r][3] * ad3);
#pragma unroll
    for (int m = 1; m < 16; m <<= 1) {
      psa += __shfl_xor(psa, m); psb += __shfl_xor(psb, m);
      pda += __shfl_xor(pda, m); pdb += __shfl_xor(pdb, m);
    }
    if ((lane & 15) == 0) {
      int hA = (lane >> 4) & 1;
      size_t row = (size_t)(row0 + r0 + r);
      als[row * 4 + hA] = psa; als[row * 4 + hA + 2] = psb;
      ald[row * 4 + hA] = pda; ald[row * 4 + hA + 2] = pdb;
    }
  }
}

// Aggregate for OUT=128, QUARTER-WAVE per node: 16 nodes per 256-thread block.
template<bool FUSE>
__global__ __launch_bounds__(256) void aggregate128_kernel(
    const unsigned* __restrict__ hb, const float* __restrict__ als, const float* __restrict__ ald,
    const int* __restrict__ row_ptr, const int* __restrict__ csr_src,
    const float* __restrict__ bias, const float* __restrict__ ln_g, const float* __restrict__ ln_b,
    float* __restrict__ out,
    const float* __restrict__ W2, const float* __restrict__ as2, const float* __restrict__ ad2,
    unsigned short* __restrict__ h2h, float* __restrict__ als2, float* __restrict__ ald2)
{
  __shared__ int s_src[4][4][17];
  __shared__ float2 s_w[4][4][17][2];
  __shared__ __align__(16) float w2s[FUSE ? 32 * 128 : 4];
  __shared__ __align__(16) float y_s[FUSE ? 16 * 132 : 4];

  int t = threadIdx.x, lane = t & 63, wid = t >> 6;
  int q = lane >> 4, c4 = lane & 15;
  int node = blockIdx.x * 16 + wid * 4 + q;   // N = 40000 = 2500*16 exact

  if constexpr (FUSE) {
#pragma unroll
    for (int p = 0; p < 4; ++p)
      async_copy16((char*)w2s + p * 4096 + t * 16, (const char*)W2 + p * 4096 + t * 16);
    __syncthreads();
  }

  int start = row_ptr[node], end = row_ptr[node + 1];
  int deg = end - start;

  float4 adq = reinterpret_cast<const float4*>(ald)[node];
  int hsel = c4 >> 3;                 // head pair (hsel, hsel+2)
  const uint4* hbase = reinterpret_cast<const uint4*>(hb + 4 * c4);
  float a0 = 0.f, a1 = 0.f, a2 = 0.f, a3 = 0.f;     // features 4c4..4c4+3
  float a4 = 0.f, a5 = 0.f, a6 = 0.f, a7 = 0.f;     // features 64+4c4..+3
  float b0 = 0.f, b1 = 0.f, b2 = 0.f, b3 = 0.f;
  float b4 = 0.f, b5 = 0.f, b6 = 0.f, b7 = 0.f;
  float ssum0 = 0.f, ssum1 = 0.f, sb0 = 0.f, sb1 = 0.f;

  for (int eb = 0; eb < deg; eb += 16) {
    int s = 0;
    float ex0 = 0.f, ex1 = 0.f, ex2 = 0.f, ex3 = 0.f;
    if (eb + c4 < deg) {
      s = csr_src[start + eb + c4];
      float4 qv = reinterpret_cast<const float4*>(als)[s];
      float v0 = qv.x + adq.x, v1 = qv.y + adq.y, v2 = qv.z + adq.z, v3 = qv.w + adq.w;
      v0 = v0 > 0.f ? v0 : 0.2f * v0; v1 = v1 > 0.f ? v1 : 0.2f * v1;
      v2 = v2 > 0.f ? v2 : 0.2f * v2; v3 = v3 > 0.f ? v3 : 0.2f * v3;
      ex0 = __expf(v0); ex1 = __expf(v1); ex2 = __expf(v2); ex3 = __expf(v3);
    }
    s_src[wid][q][c4] = s;
    s_w[wid][q][c4][0] = make_float2(ex0, ex2);
    s_w[wid][q][c4][1] = make_float2(ex1, ex3);

    int cnt = deg - eb; if (cnt > 16) cnt = 16;
    int j = 0;
    for (; j + 2 <= cnt; j += 2) {
      int sa = s_src[wid][q][j];
      int sb = s_src[wid][q][j + 1];
      uint4 ua = hbase[(size_t)sa * 16];
      uint4 ub = hbase[(size_t)sb * 16];
      float2 wa = s_w[wid][q][j][hsel];
      float2 wb = s_w[wid][q][j + 1][hsel];
      a0 = fmaf(wa.x, hlo(ua.x), a0); a1 = fmaf(wa.x, hlo(ua.y), a1);
      a2 = fmaf(wa.x, hlo(ua.z), a2); a3 = fmaf(wa.x, hlo(ua.w), a3);
      a4 = fmaf(wa.y, hhi(ua.x), a4); a5 = fmaf(wa.y, hhi(ua.y), a5);
      a6 = fmaf(wa.y, hhi(ua.z), a6); a7 = fmaf(wa.y, hhi(ua.w), a7);
      ssum0 += wa.x; ssum1 += wa.y;
      b0 = fmaf(wb.x, hlo(ub.x), b0); b1 = fmaf(wb.x, hlo(ub.y), b1);
      b2 = fmaf(wb.x, hlo(ub.z), b2); b3 = fmaf(wb.x, hlo(ub.w), b3);
      b4 = fmaf(wb.y, hhi(ub.x), b4); b5 = fmaf(wb.y, hhi(ub.y), b5);
      b6 = fmaf(wb.y, hhi(ub.z), b6); b7 = fmaf(wb.y, hhi(ub.w), b7);
      sb0 += wb.x; sb1 += wb.y;
    }
    if (j < cnt) {
      int sa = s_src[wid][q][j];
      uint4 ua = hbase[(size_t)sa * 16];
      float2 wa = s_w[wid][q][j][hsel];
      a0 = fmaf(wa.x, hlo(ua.x), a0); a1 = fmaf(wa.x, hlo(ua.y), a1);
      a2 = fmaf(wa.x, hlo(ua.z), a2); a3 = fmaf(wa.x, hlo(ua.w), a3);
      a4 = fmaf(wa.y, hhi(ua.x), a4); a5 = fmaf(wa.y, hhi(ua.y), a5);
      a6 = fmaf(wa.y, hhi(ua.z), a6); a7 = fmaf(wa.y, hhi(ua.w), a7);
      ssum0 += wa.x; ssum1 += wa.y;
    }
  }
  a0 += b0; a1 += b1; a2 += b2; a3 += b3;
  a4 += b4; a5 += b5; a6 += b6; a7 += b7;
  ssum0 += sb0; ssum1 += sb1;

  float4 blo = *reinterpret_cast<const float4*>(&bias[4 * c4]);
  float4 bhi = *reinterpret_cast<const float4*>(&bias[64 + 4 * c4]);
  float is0 = 1.f / (ssum0 + 1e-16f), is1 = 1.f / (ssum1 + 1e-16f);
  float o0 = a0 * is0 + blo.x, o1 = a1 * is0 + blo.y;
  float o2 = a2 * is0 + blo.z, o3 = a3 * is0 + blo.w;
  float o4 = a4 * is1 + bhi.x, o5 = a5 * is1 + bhi.y;
  float o6 = a6 * is1 + bhi.z, o7 = a7 * is1 + bhi.w;
  float red = (o0 + o1 + o2 + o3) + (o4 + o5 + o6 + o7);
  float sq2 = (o0 * o0 + o1 * o1 + o2 * o2 + o3 * o3)
            + (o4 * o4 + o5 * o5 + o6 * o6 + o7 * o7);
#pragma unroll
  for (int m = 1; m < 16; m <<= 1) {
    red += __shfl_xor(red, m);
    sq2 += __shfl_xor(sq2, m);
  }
  float mu = red * (1.f / 128.f);
  float var = sq2 * (1.f / 128.f) - mu * mu;
  float rstd = rsqrtf(var + 1e-5f);
  float4 glo = *reinterpret_cast<const float4*>(&ln_g[4 * c4]);
  float4 ghi = *reinterpret_cast<const float4*>(&ln_g[64 + 4 * c4]);
  float4 bl2 = *reinterpret_cast<const float4*>(&ln_b[4 * c4]);
  float4 bh2 = *reinterpret_cast<const float4*>(&ln_b[64 + 4 * c4]);
  float4 ylo, yhi;
  ylo.x = eluf((o0 - mu) * rstd * glo.x + bl2.x);
  ylo.y = eluf((o1 - mu) * rstd * glo.y + bl2.y);
  ylo.z = eluf((o2 - mu) * rstd * glo.z + bl2.z);
  ylo.w = eluf((o3 - mu) * rstd * glo.w + bl2.w);
  yhi.x = eluf((o4 - mu) * rstd * ghi.x + bh2.x);
  yhi.y = eluf((o5 - mu) * rstd * ghi.y + bh2.y);
  yhi.z = eluf((o6 - mu) * rstd * ghi.z + bh2.z);
  yhi.w = eluf((o7 - mu) * rstd * ghi.w + bh2.w);

  if constexpr (!FUSE) {
    *reinterpret_cast<float4*>(&out[(size_t)node * 128 + 4 * c4]) = ylo;
    *reinterpret_cast<float4*>(&out[(size_t)node * 128 + 64 + 4 * c4]) = yhi;
  } else {
    // broadcast y through LDS (row stride 132 -> quarter-groups on distinct banks)
    int nidx = (wid * 4 + q) * 132;
    *reinterpret_cast<float4*>(&y_s[nidx + 4 * c4]) = ylo;
    *reinterpret_cast<float4*>(&y_s[nidx + 64 + 4 * c4]) = yhi;
    // lane computes h2 cols c4 and c4+16; w2s[k*32+col]: bank==col, broadcast x4.
    float d0 = 0.f, d1 = 0.f, d2 = 0.f, d3 = 0.f;
#pragma unroll
    for (int k = 0; k < 128; k += 2) {
      float2 yv = *reinterpret_cast<const float2*>(&y_s[nidx + k]);
      d0 = fmaf(yv.x, w2s[k * 32 + c4], d0);
      d1 = fmaf(yv.y, w2s[(k + 1) * 32 + c4], d1);
      d2 = fmaf(yv.x, w2s[k * 32 + c4 + 16], d2);
      d3 = fmaf(yv.y, w2s[(k + 1) * 32 + c4 + 16], d3);
    }
    float accA = d0 + d1, accB = d2 + d3;
    unsigned pa = packh(accA, accB);
    h2h[(size_t)node * 32 + c4] = (unsigned short)(pa & 0xffffu);
    h2h[(size_t)node * 32 + c4 + 16] = (unsigned short)(pa >> 16);
    float ps = fmaf(accA, as2[c4], accB * as2[c4 + 16]);
    float pd = fmaf(accA, ad2[c4], accB * ad2[c4 + 16]);
#pragma unroll
    for (int m = 1; m < 16; m <<= 1) { ps += __shfl_xor(ps, m); pd += __shfl_xor(pd, m); }
    if (c4 == 0) { als2[node] = ps; ald2[node] = pd; }
  }
}

// Aggregate for OUT=32 (fp16 rows). QUARTER-WAVE per node; lane c4 owns
// features {2c4, 2c4+1} via one u32 load per edge.
__global__ __launch_bounds__(256) void aggregate32_kernel(
    const unsigned short* __restrict__ h, const float* __restrict__ als, const float* __restrict__ ald,
    const int* __restrict__ row_ptr, const int* __restrict__ csr_src,
    const float* __restrict__ bias, const float* __restrict__ ln_g, const float* __restrict__ ln_b,
    float* __restrict__ out, int n)
{
  __shared__ int s_src[4][4][17];
  __shared__ float s_ex[4][4][17];
  int t = threadIdx.x, lane = t & 63, wid = t >> 6;
  int q = lane >> 4, c4 = lane & 15;
  int node = blockIdx.x * 16 + wid * 4 + q;
  int start = row_ptr[node], end = row_ptr[node + 1];
  int deg = end - start;
  float adl = ald[node];
  const unsigned* hu = reinterpret_cast<const unsigned*>(h);
  float acc0 = 0.f, acc1 = 0.f, bc0 = 0.f, bc1 = 0.f;
  float ssum = 0.f, sb = 0.f;

  for (int eb = 0; eb < deg; eb += 16) {
    int s = 0; float ex = 0.f;
    if (eb + c4 < deg) {
      s = csr_src[start + eb + c4];
      float v = als[s] + adl;
      v = v > 0.f ? v : 0.2f * v;
      ex = __expf(v);
    }
    s_src[wid][q][c4] = s;
    s_ex[wid][q][c4] = ex;

    int cnt = deg - eb; if (cnt > 16) cnt = 16;
    int j = 0;
    for (; j + 2 <= cnt; j += 2) {
      int sa = s_src[wid][q][j];
      int sbx = s_src[wid][q][j + 1];
      unsigned ua = hu[(size_t)sa * 16 + c4];
      unsigned ub = hu[(size_t)sbx * 16 + c4];
      float wa = s_ex[wid][q][j];
      float wb = s_ex[wid][q][j + 1];
      acc0 = fmaf(wa, hlo(ua), acc0); acc1 = fmaf(wa, hhi(ua), acc1); ssum += wa;
      bc0 = fmaf(wb, hlo(ub), bc0); bc1 = fmaf(wb, hhi(ub), bc1); sb += wb;
    }
    if (j < cnt) {
      int sa = s_src[wid][q][j];
      unsigned ua = hu[(size_t)sa * 16 + c4];
      float wa = s_ex[wid][q][j];
      acc0 = fmaf(wa, hlo(ua), acc0); acc1 = fmaf(wa, hhi(ua), acc1); ssum += wa;
    }
  }
  acc0 += bc0; acc1 += bc1; ssum += sb;

  float2 bv = *reinterpret_cast<const float2*>(&bias[2 * c4]);
  float is = 1.f / (ssum + 1e-16f);
  float o0 = acc0 * is + bv.x;
  float o1 = acc1 * is + bv.y;
  float red = o0 + o1, sq2 = o0 * o0 + o1 * o1;
#pragma unroll
  for (int m = 1; m < 16; m <<= 1) {
    red += __shfl_xor(red, m);
    sq2 += __shfl_xor(sq2, m);
  }
  float mu = red * (1.f / 32.f);
  float var = sq2 * (1.f / 32.f) - mu * mu;
  float rstd = rsqrtf(var + 1e-5f);
  float2 gv = *reinterpret_cast<const float2*>(&ln_g[2 * c4]);
  float2 lb = *reinterpret_cast<const float2*>(&ln_b[2 * c4]);
  float2 yv;
  yv.x = eluf((o0 - mu) * rstd * gv.x + lb.x);
  yv.y = eluf((o1 - mu) * rstd * gv.y + lb.y);
  *reinterpret_cast<float2*>(&out[(size_t)node * 32 + 2 * c4]) = yv;
}

__device__ __forceinline__ int lower_bound_dev(const int* a, int n, int key) {
  int lo = 0, hi = n;
  while (lo < hi) { int mid = (lo + hi) >> 1; if (a[mid] < key) lo = mid + 1; else hi = mid; }
  return lo;
}

// Fused global mean-pool + 2-layer classifier: one block per group.
__global__ __launch_bounds__(256) void poolfc_kernel(
    const float* __restrict__ x2, const int* __restrict__ batch,
    const float* __restrict__ fc1w, const float* __restrict__ fc1b,
    const float* __restrict__ fc2w, const float* __restrict__ fc2b,
    float* __restrict__ out, int n)
{
  int g = blockIdx.x;
  int lo = lower_bound_dev(batch, n, g);
  int hi = lower_bound_dev(batch, n, g + 1);
  int t = threadIdx.x;
  int c = t & 31, r = t >> 5;
  float acc = 0.f;
  for (int i = lo + r; i < hi; i += 8) acc += x2[(size_t)i * 32 + c];
  __shared__ float red[8][32];
  __shared__ float hgl[32];
  __shared__ float zl[16];
  red[r][c] = acc;
  __syncthreads();
  if (r == 0) {
    float s = 0.f;
#pragma unroll
    for (int k = 0; k < 8; ++k) s += red[k][c];
    float cnt = (float)(hi - lo);
    hgl[c] = s / fmaxf(cnt, 1.f);
  }
  __syncthreads();
  if (t < 16) {
    float a = fc1b[t];
#pragma unroll
    for (int k = 0; k < 32; ++k) a = fmaf(hgl[k], fc1w[k * 16 + t], a);
    zl[t] = fmaxf(a, 0.f);
  }
  __syncthreads();
  if (t < 2) {
    float a = fc2b[t];
#pragma unroll
    for (int j = 0; j < 16; ++j) a = fmaf(zl[j], fc2w[j * 2 + t], a);
    out[g * 2 + t] = a;
  }
}

extern "C" void kernel_launch(void* const* d_in, const int* in_sizes, int n_in,
                              void* d_out, int out_size, void* d_ws, size_t ws_size,
                              hipStream_t stream) {
  const float* x    = (const float*)d_in[0];
  const int*   ei   = (const int*)d_in[1];
  const int*   batch= (const int*)d_in[2];
  const float* W0   = (const float*)d_in[3];
  const float* as0  = (const float*)d_in[4];
  const float* ad0  = (const float*)d_in[5];
  const float* b0   = (const float*)d_in[6];
  const float* ln0g = (const float*)d_in[7];
  const float* ln0b = (const float*)d_in[8];
  const float* W1   = (const float*)d_in[9];
  const float* as1  = (const float*)d_in[10];
  const float* ad1  = (const float*)d_in[11];
  const float* b1   = (const float*)d_in[12];
  const float* ln1g = (const float*)d_in[13];
  const float* ln1b = (const float*)d_in[14];
  const float* W2   = (const float*)d_in[15];
  const float* as2  = (const float*)d_in[16];
  const float* ad2  = (const float*)d_in[17];
  const float* b2   = (const float*)d_in[18];
  const float* ln2g = (const float*)d_in[19];
  const float* ln2b = (const float*)d_in[20];
  const float* fc1w = (const float*)d_in[21];
  const float* fc1b = (const float*)d_in[22];
  const float* fc2w = (const float*)d_in[23];
  const float* fc2b = (const float*)d_in[24];
  float* out = (float*)d_out;

  const int* srce = ei;
  const int* dste = ei + EE;

  unsigned* hb = (unsigned*)d_ws;              // N*64 packed fp16 pairs
  float* B2  = (float*)(hb + (size_t)NN * 64); // N*128
  float* als = B2 + (size_t)NN * 128;          // N*4
  float* ald = als + (size_t)NN * 4;           // N*4
  unsigned short* h2h = (unsigned short*)(ald + (size_t)NN * 4); // N*32 fp16
  float* x2  = (float*)(h2h + (size_t)NN * 32);// N*32
  float* als2 = x2 + (size_t)NN * 32;          // N
  float* ald2 = als2 + NN;                     // N
  int* deg      = (int*)(ald2 + NN);           // N
  int* row_ptr  = deg + NN;                    // N+1
  int* cursor   = row_ptr + NN + 1;            // N
  int* csr_src  = cursor + NN;                 // E
  int* bsum     = csr_src + EE;                // SCAN_BLOCKS

  // CSR build (shared by all 3 layers)
  zero_int_kernel<<<(NN + 255) / 256, 256, 0, stream>>>(deg, NN);
  count_deg_kernel<<<(EE / 2 + 255) / 256, 256, 0, stream>>>(dste, deg, EE);
  scanA_kernel<<<SCAN_BLOCKS, 1024, 0, stream>>>(deg, row_ptr, bsum, NN);
  scanC_kernel<<<SCAN_BLOCKS, 1024, 0, stream>>>(row_ptr, bsum, cursor, NN);
  scatter_kernel<<<(EE / 2 + 255) / 256, 256, 0, stream>>>(srce, dste, cursor, csr_src, EE);

  // layer 0
  gemm128_kernel<<<625, 256, 0, stream>>>(x, W0, as0, ad0, hb, als, ald);
  aggregate128_kernel<false><<<NN / 16, 256, 0, stream>>>(hb, als, ald, row_ptr, csr_src,
                                                          b0, ln0g, ln0b, B2,
                                                          nullptr, nullptr, nullptr,
                                                          nullptr, nullptr, nullptr);
  // layer 1 (+ fused layer-2 GEMM and attention projections)
  gemm128_kernel<<<625, 256, 0, stream>>>(B2, W1, as1, ad1, hb, als, ald);
  aggregate128_kernel<true><<<NN / 16, 256, 0, stream>>>(hb, als, ald, row_ptr, csr_src,
                                                         b1, ln1g, ln1b, nullptr,
                                                         W2, as2, ad2, h2h, als2, ald2);
  // layer 2 aggregate
  aggregate32_kernel<<<NN / 16, 256, 0, stream>>>(h2h, als2, ald2, row_ptr, csr_src,
                                                  b2, ln2g, ln2b, x2, NN);
  // pool + classifier (fused)
  poolfc_kernel<<<NG, 256, 0, stream>>>(x2, batch, fc1w, fc1b, fc2w, fc2b, out, NN);
}

// Round 15
// 231.887 us; speedup vs baseline: 1.1066x; 1.0550x over previous
//
#include <hip/hip_runtime.h>
#include <hip/hip_fp16.h>
#include <math.h>

#define NN 40000
#define EE 640000
#define NG 64
#define SCAN_BLOCKS ((NN + 1023) / 1024)

__device__ __forceinline__ float eluf(float x) { return x > 0.f ? x : expm1f(x); }

typedef const __attribute__((address_space(1))) char gas_char;
typedef __attribute__((address_space(3))) char las_char;

__device__ __forceinline__ void async_copy16(void* l, const void* g) {
  __builtin_amdgcn_global_load_lds((gas_char*)g, (las_char*)l, 16, 0, 0);
}

typedef __fp16 f16x2 __attribute__((ext_vector_type(2)));
__device__ __forceinline__ unsigned packh(float lo, float hi) {  // f32x2 -> packed fp16
  f16x2 p = __builtin_amdgcn_cvt_pkrtz(lo, hi);
  union { f16x2 h; unsigned u; } c; c.h = p; return c.u;
}
__device__ __forceinline__ float hlo(unsigned p) {
  union { unsigned u; f16x2 h; } c; c.u = p; return (float)c.h.x;
}
__device__ __forceinline__ float hhi(unsigned p) {
  union { unsigned u; f16x2 h; } c; c.u = p; return (float)c.h.y;
}

__global__ void zero_int_kernel(int* __restrict__ p, int n) {
  int i = blockIdx.x * 256 + threadIdx.x;
  if (i < n) p[i] = 0;
}

// 2 edges/thread (ILP2) x 1250 blocks (high TLP).
__global__ void count_deg_kernel(const int* __restrict__ dst, int* __restrict__ deg, int e) {
  int i0 = (blockIdx.x * 256 + threadIdx.x) * 2;
  if (i0 + 2 <= e) {
    int2 d2 = *reinterpret_cast<const int2*>(&dst[i0]);
    atomicAdd(&deg[d2.x], 1);
    atomicAdd(&deg[d2.y], 1);
  } else {
    for (int i = i0; i < e; ++i) atomicAdd(&deg[dst[i]], 1);
  }
}

__global__ __launch_bounds__(1024) void scanA_kernel(const int* __restrict__ deg,
                                                     int* __restrict__ row_ptr,
                                                     int* __restrict__ bsum, int n) {
  __shared__ int wsum[16];
  int t = threadIdx.x, lane = t & 63, wid = t >> 6;
  int i = blockIdx.x * 1024 + t;
  int v = (i < n) ? deg[i] : 0;
#pragma unroll
  for (int off = 1; off < 64; off <<= 1) {
    int u = __shfl_up(v, off);
    if (lane >= off) v += u;
  }
  if (lane == 63) wsum[wid] = v;
  __syncthreads();
  if (t < 16) {
    int w = wsum[t];
#pragma unroll
    for (int off = 1; off < 16; off <<= 1) {
      int u = __shfl_up(w, off);
      if (t >= off) w += u;
    }
    wsum[t] = w;
  }
  __syncthreads();
  if (wid > 0) v += wsum[wid - 1];
  if (i < n) row_ptr[i + 1] = v;
  if (t == 1023) bsum[blockIdx.x] = v;
}

// scanC with inlined block-offset reduce (scanB merged).
__global__ __launch_bounds__(1024) void scanC_kernel(int* __restrict__ row_ptr,
                                                     const int* __restrict__ bsum,
                                                     int* __restrict__ cursor, int n) {
  __shared__ int off_s;
  int t = threadIdx.x;
  int b = blockIdx.x;
  if (t < 64) {
    int v = (t < b && t < SCAN_BLOCKS) ? bsum[t] : 0;
#pragma unroll
    for (int m = 1; m < 64; m <<= 1) v += __shfl_xor(v, m);
    if (t == 0) off_s = v;
  }
  __syncthreads();
  int off = off_s;
  int i = b * 1024 + t;
  if (i < n) {
    int v = row_ptr[i + 1] + off;
    row_ptr[i + 1] = v;
    if (i + 1 < n) cursor[i + 1] = v;
    if (i == 0) { cursor[0] = 0; row_ptr[0] = 0; }
  }
}

// MERGED dispatch: 1875 blocks. bx%3==2 -> gemm128-L0 tile (625 tiles);
// else -> scatter chunk (1250 chunks x 512 edges). Scatter is latency-bound
// with idle VALU; interleaving gives its CUs the GEMM's VALU work.
__global__ __launch_bounds__(256, 3) void gemm_scatter_kernel(
    const float* __restrict__ x, const float* __restrict__ W,
    const float* __restrict__ a_s, const float* __restrict__ a_d,
    unsigned* __restrict__ hb, float* __restrict__ als, float* __restrict__ ald,
    const int* __restrict__ src, const int* __restrict__ dst,
    int* __restrict__ cursor, int* __restrict__ csr_src, int e)
{
  __shared__ float xs[2][64 * 32];
  __shared__ float ws[2][32 * 128];

  int bx = blockIdx.x;
  int t = threadIdx.x;

  if (bx % 3 != 2) {
    // ---- scatter part ----
    int sid = (bx / 3) * 2 + (bx % 3 == 1 ? 1 : 0);
    int i0 = (sid * 256 + t) * 2;
    if (i0 + 2 <= e) {
      int2 s2 = *reinterpret_cast<const int2*>(&src[i0]);
      int2 d2 = *reinterpret_cast<const int2*>(&dst[i0]);
      int p0 = atomicAdd(&cursor[d2.x], 1);
      int p1 = atomicAdd(&cursor[d2.y], 1);
      csr_src[p0] = s2.x;
      csr_src[p1] = s2.y;
    } else {
      for (int i = i0; i < e; ++i) {
        int d = dst[i];
        int pos = atomicAdd(&cursor[d], 1);
        csr_src[pos] = src[i];
      }
    }
    return;
  }

  // ---- gemm part ----
  int row0 = (bx / 3) * 64;
  const char* xgb = (const char*)x + (size_t)row0 * 512;

  {
    int li0 = t, li1 = t + 256;
    async_copy16((char*)xs[0] + li0 * 16, xgb + (li0 >> 3) * 512 + (li0 & 7) * 16);
    async_copy16((char*)xs[0] + li1 * 16, xgb + (li1 >> 3) * 512 + (li1 & 7) * 16);
    const char* wg = (const char*)W;
#pragma unroll
    for (int p = 0; p < 4; ++p)
      async_copy16((char*)ws[0] + p * 4096 + t * 16, wg + p * 4096 + t * 16);
  }
  __syncthreads();

  int cg = t & 31, rg = t >> 5;
  int r0 = rg * 8;
  int jlo = 2 * cg;

  float acc[8][4];
#pragma unroll
  for (int r = 0; r < 8; ++r)
#pragma unroll
    for (int c = 0; c < 4; ++c) acc[r][c] = 0.f;

  for (int ch = 0; ch < 4; ++ch) {
    if (ch < 3) {
      int b = (ch + 1) & 1;
      int li0 = t, li1 = t + 256;
      const char* xg = xgb + (ch + 1) * 128;
      async_copy16((char*)xs[b] + li0 * 16, xg + (li0 >> 3) * 512 + (li0 & 7) * 16);
      async_copy16((char*)xs[b] + li1 * 16, xg + (li1 >> 3) * 512 + (li1 & 7) * 16);
      const char* wg = (const char*)W + (size_t)(ch + 1) * 32 * 128 * 4;
#pragma unroll
      for (int p = 0; p < 4; ++p)
        async_copy16((char*)ws[b] + p * 4096 + t * 16, wg + p * 4096 + t * 16);
    }
    const float* wc = ws[ch & 1];
    const float* xc = xs[ch & 1];
#pragma unroll
    for (int kk = 0; kk < 32; kk += 4) {
      float2 wlo[4], whi[4];
#pragma unroll
      for (int q = 0; q < 4; ++q) {
        wlo[q] = *reinterpret_cast<const float2*>(&wc[(kk + q) * 128 + jlo]);
        whi[q] = *reinterpret_cast<const float2*>(&wc[(kk + q) * 128 + 64 + jlo]);
      }
#pragma unroll
      for (int r = 0; r < 8; ++r) {
        float4 xv = *reinterpret_cast<const float4*>(&xc[(r0 + r) * 32 + kk]);
        float a0 = acc[r][0], a1 = acc[r][1], a2 = acc[r][2], a3 = acc[r][3];
        a0 = fmaf(xv.x, wlo[0].x, a0); a1 = fmaf(xv.x, wlo[0].y, a1);
        a2 = fmaf(xv.x, whi[0].x, a2); a3 = fmaf(xv.x, whi[0].y, a3);
        a0 = fmaf(xv.y, wlo[1].x, a0); a1 = fmaf(xv.y, wlo[1].y, a1);
        a2 = fmaf(xv.y, whi[1].x, a2); a3 = fmaf(xv.y, whi[1].y, a3);
        a0 = fmaf(xv.z, wlo[2].x, a0); a1 = fmaf(xv.z, wlo[2].y, a1);
        a2 = fmaf(xv.z, whi[2].x, a2); a3 = fmaf(xv.z, whi[2].y, a3);
        a0 = fmaf(xv.w, wlo[3].x, a0); a1 = fmaf(xv.w, wlo[3].y, a1);
        a2 = fmaf(xv.w, whi[3].x, a2); a3 = fmaf(xv.w, whi[3].y, a3);
        acc[r][0] = a0; acc[r][1] = a1; acc[r][2] = a2; acc[r][3] = a3;
      }
    }
    __syncthreads();
  }

#pragma unroll
  for (int r = 0; r < 8; ++r) {
    uint2 pv;
    pv.x = packh(acc[r][0], acc[r][2]);
    pv.y = packh(acc[r][1], acc[r][3]);
    *reinterpret_cast<uint2*>(&hb[(size_t)(row0 + r0 + r) * 64 + jlo]) = pv;
  }

  float as0 = a_s[jlo], as1 = a_s[jlo + 1], as2 = a_s[jlo + 64], as3 = a_s[jlo + 65];
  float ad0 = a_d[jlo], ad1 = a_d[jlo + 1], ad2 = a_d[jlo + 64], ad3 = a_d[jlo + 65];
  int lane = t & 63;
#pragma unroll
  for (int r = 0; r < 8; ++r) {
    float psa = fmaf(acc[r][0], as0, acc[r][1] * as1);
    float psb = fmaf(acc[r][2], as2, acc[r][3] * as3);
    float pda = fmaf(acc[r][0], ad0, acc[r][1] * ad1);
    float pdb = fmaf(acc[r][2], ad2, acc[r][3] * ad3);
#pragma unroll
    for (int m = 1; m < 16; m <<= 1) {
      psa += __shfl_xor(psa, m); psb += __shfl_xor(psb, m);
      pda += __shfl_xor(pda, m); pdb += __shfl_xor(pdb, m);
    }
    if ((lane & 15) == 0) {
      int hA = (lane >> 4) & 1;
      size_t row = (size_t)(row0 + r0 + r);
      als[row * 4 + hA] = psa; als[row * 4 + hA + 2] = psb;
      ald[row * 4 + hA] = pda; ald[row * 4 + hA + 2] = pdb;
    }
  }
}

// Standalone GEMM (K=128, OUT=128) for layer 1.
__global__ __launch_bounds__(256, 3) void gemm128_kernel(
    const float* __restrict__ x, const float* __restrict__ W,
    const float* __restrict__ a_s, const float* __restrict__ a_d,
    unsigned* __restrict__ hb, float* __restrict__ als, float* __restrict__ ald)
{
  __shared__ float xs[2][64 * 32];
  __shared__ float ws[2][32 * 128];

  int t = threadIdx.x;
  int row0 = blockIdx.x * 64;
  const char* xgb = (const char*)x + (size_t)row0 * 512;

  {
    int li0 = t, li1 = t + 256;
    async_copy16((char*)xs[0] + li0 * 16, xgb + (li0 >> 3) * 512 + (li0 & 7) * 16);
    async_copy16((char*)xs[0] + li1 * 16, xgb + (li1 >> 3) * 512 + (li1 & 7) * 16);
    const char* wg = (const char*)W;
#pragma unroll
    for (int p = 0; p < 4; ++p)
      async_copy16((char*)ws[0] + p * 4096 + t * 16, wg + p * 4096 + t * 16);
  }
  __syncthreads();

  int cg = t & 31, rg = t >> 5;
  int r0 = rg * 8;
  int jlo = 2 * cg;

  float acc[8][4];
#pragma unroll
  for (int r = 0; r < 8; ++r)
#pragma unroll
    for (int c = 0; c < 4; ++c) acc[r][c] = 0.f;

  for (int ch = 0; ch < 4; ++ch) {
    if (ch < 3) {
      int b = (ch + 1) & 1;
      int li0 = t, li1 = t + 256;
      const char* xg = xgb + (ch + 1) * 128;
      async_copy16((char*)xs[b] + li0 * 16, xg + (li0 >> 3) * 512 + (li0 & 7) * 16);
      async_copy16((char*)xs[b] + li1 * 16, xg + (li1 >> 3) * 512 + (li1 & 7) * 16);
      const char* wg = (const char*)W + (size_t)(ch + 1) * 32 * 128 * 4;
#pragma unroll
      for (int p = 0; p < 4; ++p)
        async_copy16((char*)ws[b] + p * 4096 + t * 16, wg + p * 4096 + t * 16);
    }
    const float* wc = ws[ch & 1];
    const float* xc = xs[ch & 1];
#pragma unroll
    for (int kk = 0; kk < 32; kk += 4) {
      float2 wlo[4], whi[4];
#pragma unroll
      for (int q = 0; q < 4; ++q) {
        wlo[q] = *reinterpret_cast<const float2*>(&wc[(kk + q) * 128 + jlo]);
        whi[q] = *reinterpret_cast<const float2*>(&wc[(kk + q) * 128 + 64 + jlo]);
      }
#pragma unroll
      for (int r = 0; r < 8; ++r) {
        float4 xv = *reinterpret_cast<const float4*>(&xc[(r0 + r) * 32 + kk]);
        float a0 = acc[r][0], a1 = acc[r][1], a2 = acc[r][2], a3 = acc[r][3];
        a0 = fmaf(xv.x, wlo[0].x, a0); a1 = fmaf(xv.x, wlo[0].y, a1);
        a2 = fmaf(xv.x, whi[0].x, a2); a3 = fmaf(xv.x, whi[0].y, a3);
        a0 = fmaf(xv.y, wlo[1].x, a0); a1 = fmaf(xv.y, wlo[1].y, a1);
        a2 = fmaf(xv.y, whi[1].x, a2); a3 = fmaf(xv.y, whi[1].y, a3);
        a0 = fmaf(xv.z, wlo[2].x, a0); a1 = fmaf(xv.z, wlo[2].y, a1);
        a2 = fmaf(xv.z, whi[2].x, a2); a3 = fmaf(xv.z, whi[2].y, a3);
        a0 = fmaf(xv.w, wlo[3].x, a0); a1 = fmaf(xv.w, wlo[3].y, a1);
        a2 = fmaf(xv.w, whi[3].x, a2); a3 = fmaf(xv.w, whi[3].y, a3);
        acc[r][0] = a0; acc[r][1] = a1; acc[r][2] = a2; acc[r][3] = a3;
      }
    }
    __syncthreads();
  }

#pragma unroll
  for (int r = 0; r < 8; ++r) {
    uint2 pv;
    pv.x = packh(acc[r][0], acc[r][2]);
    pv.y = packh(acc[r][1], acc[r][3]);
    *reinterpret_cast<uint2*>(&hb[(size_t)(row0 + r0 + r) * 64 + jlo]) = pv;
  }

  float as0 = a_s[jlo], as1 = a_s[jlo + 1], as2 = a_s[jlo + 64], as3 = a_s[jlo + 65];
  float ad0 = a_d[jlo], ad1 = a_d[jlo + 1], ad2 = a_d[jlo + 64], ad3 = a_d[jlo + 65];
  int lane = t & 63;
#pragma unroll
  for (int r = 0; r < 8; ++r) {
    float psa = fmaf(acc[r][0], as0, acc[r][1] * as1);
    float psb = fmaf(acc[r][2], as2, acc[r][3] * as3);
    float pda = fmaf(acc[r][0], ad0, acc[r][1] * ad1);
    float pdb = fmaf(acc[r][2], ad2, acc[r][3] * ad3);
#pragma unroll
    for (int m = 1; m < 16; m <<= 1) {
      psa += __shfl_xor(psa, m); psb += __shfl_xor(psb, m);
      pda += __shfl_xor(pda, m); pdb += __shfl_xor(pdb, m);
    }
    if ((lane & 15) == 0) {
      int hA = (lane >> 4) & 1;
      size_t row = (size_t)(row0 + r0 + r);
      als[row * 4 + hA] = psa; als[row * 4 + hA + 2] = psb;
      ald[row * 4 + hA] = pda; ald[row * 4 + hA + 2] = pdb;
    }
  }
}

// Aggregate for OUT=128, QUARTER-WAVE per node: 16 nodes per 256-thread block.
template<bool FUSE>
__global__ __launch_bounds__(256) void aggregate128_kernel(
    const unsigned* __restrict__ hb, const float* __restrict__ als, const float* __restrict__ ald,
    const int* __restrict__ row_ptr, const int* __restrict__ csr_src,
    const float* __restrict__ bias, const float* __restrict__ ln_g, const float* __restrict__ ln_b,
    float* __restrict__ out,
    const float* __restrict__ W2, const float* __restrict__ as2, const float* __restrict__ ad2,
    unsigned short* __restrict__ h2h, float* __restrict__ als2, float* __restrict__ ald2)
{
  __shared__ int s_src[4][4][17];
  __shared__ float2 s_w[4][4][17][2];
  __shared__ __align__(16) float w2s[FUSE ? 32 * 128 : 4];
  __shared__ __align__(16) float y_s[FUSE ? 16 * 132 : 4];

  int t = threadIdx.x, lane = t & 63, wid = t >> 6;
  int q = lane >> 4, c4 = lane & 15;
  int node = blockIdx.x * 16 + wid * 4 + q;   // N = 40000 = 2500*16 exact

  if constexpr (FUSE) {
#pragma unroll
    for (int p = 0; p < 4; ++p)
      async_copy16((char*)w2s + p * 4096 + t * 16, (const char*)W2 + p * 4096 + t * 16);
    __syncthreads();
  }

  int start = row_ptr[node], end = row_ptr[node + 1];
  int deg = end - start;

  float4 adq = reinterpret_cast<const float4*>(ald)[node];
  int hsel = c4 >> 3;                 // head pair (hsel, hsel+2)
  const uint4* hbase = reinterpret_cast<const uint4*>(hb + 4 * c4);
  float a0 = 0.f, a1 = 0.f, a2 = 0.f, a3 = 0.f;     // features 4c4..4c4+3
  float a4 = 0.f, a5 = 0.f, a6 = 0.f, a7 = 0.f;     // features 64+4c4..+3
  float b0 = 0.f, b1 = 0.f, b2 = 0.f, b3 = 0.f;
  float b4 = 0.f, b5 = 0.f, b6 = 0.f, b7 = 0.f;
  float ssum0 = 0.f, ssum1 = 0.f, sb0 = 0.f, sb1 = 0.f;

  for (int eb = 0; eb < deg; eb += 16) {
    int s = 0;
    float ex0 = 0.f, ex1 = 0.f, ex2 = 0.f, ex3 = 0.f;
    if (eb + c4 < deg) {
      s = csr_src[start + eb + c4];
      float4 qv = reinterpret_cast<const float4*>(als)[s];
      float v0 = qv.x + adq.x, v1 = qv.y + adq.y, v2 = qv.z + adq.z, v3 = qv.w + adq.w;
      v0 = v0 > 0.f ? v0 : 0.2f * v0; v1 = v1 > 0.f ? v1 : 0.2f * v1;
      v2 = v2 > 0.f ? v2 : 0.2f * v2; v3 = v3 > 0.f ? v3 : 0.2f * v3;
      ex0 = __expf(v0); ex1 = __expf(v1); ex2 = __expf(v2); ex3 = __expf(v3);
    }
    s_src[wid][q][c4] = s;
    s_w[wid][q][c4][0] = make_float2(ex0, ex2);
    s_w[wid][q][c4][1] = make_float2(ex1, ex3);

    int cnt = deg - eb; if (cnt > 16) cnt = 16;
    int j = 0;
    for (; j + 2 <= cnt; j += 2) {
      int sa = s_src[wid][q][j];
      int sb = s_src[wid][q][j + 1];
      uint4 ua = hbase[(size_t)sa * 16];
      uint4 ub = hbase[(size_t)sb * 16];
      float2 wa = s_w[wid][q][j][hsel];
      float2 wb = s_w[wid][q][j + 1][hsel];
      a0 = fmaf(wa.x, hlo(ua.x), a0); a1 = fmaf(wa.x, hlo(ua.y), a1);
      a2 = fmaf(wa.x, hlo(ua.z), a2); a3 = fmaf(wa.x, hlo(ua.w), a3);
      a4 = fmaf(wa.y, hhi(ua.x), a4); a5 = fmaf(wa.y, hhi(ua.y), a5);
      a6 = fmaf(wa.y, hhi(ua.z), a6); a7 = fmaf(wa.y, hhi(ua.w), a7);
      ssum0 += wa.x; ssum1 += wa.y;
      b0 = fmaf(wb.x, hlo(ub.x), b0); b1 = fmaf(wb.x, hlo(ub.y), b1);
      b2 = fmaf(wb.x, hlo(ub.z), b2); b3 = fmaf(wb.x, hlo(ub.w), b3);
      b4 = fmaf(wb.y, hhi(ub.x), b4); b5 = fmaf(wb.y, hhi(ub.y), b5);
      b6 = fmaf(wb.y, hhi(ub.z), b6); b7 = fmaf(wb.y, hhi(ub.w), b7);
      sb0 += wb.x; sb1 += wb.y;
    }
    if (j < cnt) {
      int sa = s_src[wid][q][j];
      uint4 ua = hbase[(size_t)sa * 16];
      float2 wa = s_w[wid][q][j][hsel];
      a0 = fmaf(wa.x, hlo(ua.x), a0); a1 = fmaf(wa.x, hlo(ua.y), a1);
      a2 = fmaf(wa.x, hlo(ua.z), a2); a3 = fmaf(wa.x, hlo(ua.w), a3);
      a4 = fmaf(wa.y, hhi(ua.x), a4); a5 = fmaf(wa.y, hhi(ua.y), a5);
      a6 = fmaf(wa.y, hhi(ua.z), a6); a7 = fmaf(wa.y, hhi(ua.w), a7);
      ssum0 += wa.x; ssum1 += wa.y;
    }
  }
  a0 += b0; a1 += b1; a2 += b2; a3 += b3;
  a4 += b4; a5 += b5; a6 += b6; a7 += b7;
  ssum0 += sb0; ssum1 += sb1;

  float4 blo = *reinterpret_cast<const float4*>(&bias[4 * c4]);
  float4 bhi = *reinterpret_cast<const float4*>(&bias[64 + 4 * c4]);
  float is0 = 1.f / (ssum0 + 1e-16f), is1 = 1.f / (ssum1 + 1e-16f);
  float o0 = a0 * is0 + blo.x, o1 = a1 * is0 + blo.y;
  float o2 = a2 * is0 + blo.z, o3 = a3 * is0 + blo.w;
  float o4 = a4 * is1 + bhi.x, o5 = a5 * is1 + bhi.y;
  float o6 = a6 * is1 + bhi.z, o7 = a7 * is1 + bhi.w;
  float red = (o0 + o1 + o2 + o3) + (o4 + o5 + o6 + o7);
  float sq2 = (o0 * o0 + o1 * o1 + o2 * o2 + o3 * o3)
            + (o4 * o4 + o5 * o5 + o6 * o6 + o7 * o7);
#pragma unroll
  for (int m = 1; m < 16; m <<= 1) {
    red += __shfl_xor(red, m);
    sq2 += __shfl_xor(sq2, m);
  }
  float mu = red * (1.f / 128.f);
  float var = sq2 * (1.f / 128.f) - mu * mu;
  float rstd = rsqrtf(var + 1e-5f);
  float4 glo = *reinterpret_cast<const float4*>(&ln_g[4 * c4]);
  float4 ghi = *reinterpret_cast<const float4*>(&ln_g[64 + 4 * c4]);
  float4 bl2 = *reinterpret_cast<const float4*>(&ln_b[4 * c4]);
  float4 bh2 = *reinterpret_cast<const float4*>(&ln_b[64 + 4 * c4]);
  float4 ylo, yhi;
  ylo.x = eluf((o0 - mu) * rstd * glo.x + bl2.x);
  ylo.y = eluf((o1 - mu) * rstd * glo.y + bl2.y);
  ylo.z = eluf((o2 - mu) * rstd * glo.z + bl2.z);
  ylo.w = eluf((o3 - mu) * rstd * glo.w + bl2.w);
  yhi.x = eluf((o4 - mu) * rstd * ghi.x + bh2.x);
  yhi.y = eluf((o5 - mu) * rstd * ghi.y + bh2.y);
  yhi.z = eluf((o6 - mu) * rstd * ghi.z + bh2.z);
  yhi.w = eluf((o7 - mu) * rstd * ghi.w + bh2.w);

  if constexpr (!FUSE) {
    *reinterpret_cast<float4*>(&out[(size_t)node * 128 + 4 * c4]) = ylo;
    *reinterpret_cast<float4*>(&out[(size_t)node * 128 + 64 + 4 * c4]) = yhi;
  } else {
    // broadcast y through LDS (row stride 132 -> quarter-groups on distinct banks)
    int nidx = (wid * 4 + q) * 132;
    *reinterpret_cast<float4*>(&y_s[nidx + 4 * c4]) = ylo;
    *reinterpret_cast<float4*>(&y_s[nidx + 64 + 4 * c4]) = yhi;
    // lane computes h2 cols c4 and c4+16; w2s[k*32+col]: bank==col, broadcast x4.
    float d0 = 0.f, d1 = 0.f, d2 = 0.f, d3 = 0.f;
#pragma unroll
    for (int k = 0; k < 128; k += 2) {
      float2 yv = *reinterpret_cast<const float2*>(&y_s[nidx + k]);
      d0 = fmaf(yv.x, w2s[k * 32 + c4], d0);
      d1 = fmaf(yv.y, w2s[(k + 1) * 32 + c4], d1);
      d2 = fmaf(yv.x, w2s[k * 32 + c4 + 16], d2);
      d3 = fmaf(yv.y, w2s[(k + 1) * 32 + c4 + 16], d3);
    }
    float accA = d0 + d1, accB = d2 + d3;
    unsigned pa = packh(accA, accB);
    h2h[(size_t)node * 32 + c4] = (unsigned short)(pa & 0xffffu);
    h2h[(size_t)node * 32 + c4 + 16] = (unsigned short)(pa >> 16);
    float ps = fmaf(accA, as2[c4], accB * as2[c4 + 16]);
    float pd = fmaf(accA, ad2[c4], accB * ad2[c4 + 16]);
#pragma unroll
    for (int m = 1; m < 16; m <<= 1) { ps += __shfl_xor(ps, m); pd += __shfl_xor(pd, m); }
    if (c4 == 0) { als2[node] = ps; ald2[node] = pd; }
  }
}

// Aggregate for OUT=32 (fp16 rows). QUARTER-WAVE per node; lane c4 owns
// features {2c4, 2c4+1} via one u32 load per edge.
__global__ __launch_bounds__(256) void aggregate32_kernel(
    const unsigned short* __restrict__ h, const float* __restrict__ als, const float* __restrict__ ald,
    const int* __restrict__ row_ptr, const int* __restrict__ csr_src,
    const float* __restrict__ bias, const float* __restrict__ ln_g, const float* __restrict__ ln_b,
    float* __restrict__ out, int n)
{
  __shared__ int s_src[4][4][17];
  __shared__ float s_ex[4][4][17];
  int t = threadIdx.x, lane = t & 63, wid = t >> 6;
  int q = lane >> 4, c4 = lane & 15;
  int node = blockIdx.x * 16 + wid * 4 + q;
  int start = row_ptr[node], end = row_ptr[node + 1];
  int deg = end - start;
  float adl = ald[node];
  const unsigned* hu = reinterpret_cast<const unsigned*>(h);
  float acc0 = 0.f, acc1 = 0.f, bc0 = 0.f, bc1 = 0.f;
  float ssum = 0.f, sb = 0.f;

  for (int eb = 0; eb < deg; eb += 16) {
    int s = 0; float ex = 0.f;
    if (eb + c4 < deg) {
      s = csr_src[start + eb + c4];
      float v = als[s] + adl;
      v = v > 0.f ? v : 0.2f * v;
      ex = __expf(v);
    }
    s_src[wid][q][c4] = s;
    s_ex[wid][q][c4] = ex;

    int cnt = deg - eb; if (cnt > 16) cnt = 16;
    int j = 0;
    for (; j + 2 <= cnt; j += 2) {
      int sa = s_src[wid][q][j];
      int sbx = s_src[wid][q][j + 1];
      unsigned ua = hu[(size_t)sa * 16 + c4];
      unsigned ub = hu[(size_t)sbx * 16 + c4];
      float wa = s_ex[wid][q][j];
      float wb = s_ex[wid][q][j + 1];
      acc0 = fmaf(wa, hlo(ua), acc0); acc1 = fmaf(wa, hhi(ua), acc1); ssum += wa;
      bc0 = fmaf(wb, hlo(ub), bc0); bc1 = fmaf(wb, hhi(ub), bc1); sb += wb;
    }
    if (j < cnt) {
      int sa = s_src[wid][q][j];
      unsigned ua = hu[(size_t)sa * 16 + c4];
      float wa = s_ex[wid][q][j];
      acc0 = fmaf(wa, hlo(ua), acc0); acc1 = fmaf(wa, hhi(ua), acc1); ssum += wa;
    }
  }
  acc0 += bc0; acc1 += bc1; ssum += sb;

  float2 bv = *reinterpret_cast<const float2*>(&bias[2 * c4]);
  float is = 1.f / (ssum + 1e-16f);
  float o0 = acc0 * is + bv.x;
  float o1 = acc1 * is + bv.y;
  float red = o0 + o1, sq2 = o0 * o0 + o1 * o1;
#pragma unroll
  for (int m = 1; m < 16; m <<= 1) {
    red += __shfl_xor(red, m);
    sq2 += __shfl_xor(sq2, m);
  }
  float mu = red * (1.f / 32.f);
  float var = sq2 * (1.f / 32.f) - mu * mu;
  float rstd = rsqrtf(var + 1e-5f);
  float2 gv = *reinterpret_cast<const float2*>(&ln_g[2 * c4]);
  float2 lb = *reinterpret_cast<const float2*>(&ln_b[2 * c4]);
  float2 yv;
  yv.x = eluf((o0 - mu) * rstd * gv.x + lb.x);
  yv.y = eluf((o1 - mu) * rstd * gv.y + lb.y);
  *reinterpret_cast<float2*>(&out[(size_t)node * 32 + 2 * c4]) = yv;
}

__device__ __forceinline__ int lower_bound_dev(const int* a, int n, int key) {
  int lo = 0, hi = n;
  while (lo < hi) { int mid = (lo + hi) >> 1; if (a[mid] < key) lo = mid + 1; else hi = mid; }
  return lo;
}

// Fused global mean-pool + 2-layer classifier: one block per group.
__global__ __launch_bounds__(256) void poolfc_kernel(
    const float* __restrict__ x2, const int* __restrict__ batch,
    const float* __restrict__ fc1w, const float* __restrict__ fc1b,
    const float* __restrict__ fc2w, const float* __restrict__ fc2b,
    float* __restrict__ out, int n)
{
  int g = blockIdx.x;
  int lo = lower_bound_dev(batch, n, g);
  int hi = lower_bound_dev(batch, n, g + 1);
  int t = threadIdx.x;
  int c = t & 31, r = t >> 5;
  float acc = 0.f;
  for (int i = lo + r; i < hi; i += 8) acc += x2[(size_t)i * 32 + c];
  __shared__ float red[8][32];
  __shared__ float hgl[32];
  __shared__ float zl[16];
  red[r][c] = acc;
  __syncthreads();
  if (r == 0) {
    float s = 0.f;
#pragma unroll
    for (int k = 0; k < 8; ++k) s += red[k][c];
    float cnt = (float)(hi - lo);
    hgl[c] = s / fmaxf(cnt, 1.f);
  }
  __syncthreads();
  if (t < 16) {
    float a = fc1b[t];
#pragma unroll
    for (int k = 0; k < 32; ++k) a = fmaf(hgl[k], fc1w[k * 16 + t], a);
    zl[t] = fmaxf(a, 0.f);
  }
  __syncthreads();
  if (t < 2) {
    float a = fc2b[t];
#pragma unroll
    for (int j = 0; j < 16; ++j) a = fmaf(zl[j], fc2w[j * 2 + t], a);
    out[g * 2 + t] = a;
  }
}

extern "C" void kernel_launch(void* const* d_in, const int* in_sizes, int n_in,
                              void* d_out, int out_size, void* d_ws, size_t ws_size,
                              hipStream_t stream) {
  const float* x    = (const float*)d_in[0];
  const int*   ei   = (const int*)d_in[1];
  const int*   batch= (const int*)d_in[2];
  const float* W0   = (const float*)d_in[3];
  const float* as0  = (const float*)d_in[4];
  const float* ad0  = (const float*)d_in[5];
  const float* b0   = (const float*)d_in[6];
  const float* ln0g = (const float*)d_in[7];
  const float* ln0b = (const float*)d_in[8];
  const float* W1   = (const float*)d_in[9];
  const float* as1  = (const float*)d_in[10];
  const float* ad1  = (const float*)d_in[11];
  const float* b1   = (const float*)d_in[12];
  const float* ln1g = (const float*)d_in[13];
  const float* ln1b = (const float*)d_in[14];
  const float* W2   = (const float*)d_in[15];
  const float* as2  = (const float*)d_in[16];
  const float* ad2  = (const float*)d_in[17];
  const float* b2   = (const float*)d_in[18];
  const float* ln2g = (const float*)d_in[19];
  const float* ln2b = (const float*)d_in[20];
  const float* fc1w = (const float*)d_in[21];
  const float* fc1b = (const float*)d_in[22];
  const float* fc2w = (const float*)d_in[23];
  const float* fc2b = (const float*)d_in[24];
  float* out = (float*)d_out;

  const int* srce = ei;
  const int* dste = ei + EE;

  unsigned* hb = (unsigned*)d_ws;              // N*64 packed fp16 pairs
  float* B2  = (float*)(hb + (size_t)NN * 64); // N*128
  float* als = B2 + (size_t)NN * 128;          // N*4
  float* ald = als + (size_t)NN * 4;           // N*4
  unsigned short* h2h = (unsigned short*)(ald + (size_t)NN * 4); // N*32 fp16
  float* x2  = (float*)(h2h + (size_t)NN * 32);// N*32
  float* als2 = x2 + (size_t)NN * 32;          // N
  float* ald2 = als2 + NN;                     // N
  int* deg      = (int*)(ald2 + NN);           // N
  int* row_ptr  = deg + NN;                    // N+1
  int* cursor   = row_ptr + NN + 1;            // N
  int* csr_src  = cursor + NN;                 // E
  int* bsum     = csr_src + EE;                // SCAN_BLOCKS

  // CSR build prefix (count + scan)
  zero_int_kernel<<<(NN + 255) / 256, 256, 0, stream>>>(deg, NN);
  count_deg_kernel<<<(EE / 2 + 255) / 256, 256, 0, stream>>>(dste, deg, EE);
  scanA_kernel<<<SCAN_BLOCKS, 1024, 0, stream>>>(deg, row_ptr, bsum, NN);
  scanC_kernel<<<SCAN_BLOCKS, 1024, 0, stream>>>(row_ptr, bsum, cursor, NN);

  // MERGED: scatter (1250 blocks) + layer-0 gemm (625 blocks), interleaved
  gemm_scatter_kernel<<<1875, 256, 0, stream>>>(x, W0, as0, ad0, hb, als, ald,
                                                srce, dste, cursor, csr_src, EE);

  // layer 0 aggregate
  aggregate128_kernel<false><<<NN / 16, 256, 0, stream>>>(hb, als, ald, row_ptr, csr_src,
                                                          b0, ln0g, ln0b, B2,
                                                          nullptr, nullptr, nullptr,
                                                          nullptr, nullptr, nullptr);
  // layer 1 (+ fused layer-2 GEMM and attention projections)
  gemm128_kernel<<<625, 256, 0, stream>>>(B2, W1, as1, ad1, hb, als, ald);
  aggregate128_kernel<true><<<NN / 16, 256, 0, stream>>>(hb, als, ald, row_ptr, csr_src,
                                                         b1, ln1g, ln1b, nullptr,
                                                         W2, as2, ad2, h2h, als2, ald2);
  // layer 2 aggregate
  aggregate32_kernel<<<NN / 16, 256, 0, stream>>>(h2h, als2, ald2, row_ptr, csr_src,
                                                  b2, ln2g, ln2b, x2, NN);
  // pool + classifier (fused)
  poolfc_kernel<<<NG, 256, 0, stream>>>(x2, batch, fc1w, fc1b, fc2w, fc2b, out, NN);
}